// Round 5
// baseline (820.283 us; speedup 1.0000x reference)
//
#include <hip/hip_runtime.h>
#include <stdint.h>

typedef unsigned short u16;
typedef __attribute__((ext_vector_type(8))) short short8;
typedef __attribute__((ext_vector_type(4))) float floatx4;

#define RS66  (66*128)
#define IS66  (66*66*128)
#define RS130 (130*128)
#define IS130 (130*130*128)

__device__ __forceinline__ float bf2f(u16 h) {
  union { unsigned u; float f; } v; v.u = ((unsigned)h) << 16; return v.f;
}
__device__ __forceinline__ u16 f2bf(float f) {
  union { float f; unsigned u; } v; v.f = f;
  unsigned r = v.u + 0x7FFFu + ((v.u >> 16) & 1u);
  return (u16)(r >> 16);
}
__device__ __forceinline__ unsigned fkey(float f) {
  unsigned u = __float_as_uint(f);
  return (u & 0x80000000u) ? ~u : (u | 0x80000000u);
}
// LDS-visibility barrier: drain own ds_writes (lgkmcnt), then join. Global loads
// (register-destined) ride across freely; their waits are compiler-managed via
// real register dependencies. No manual vmcnt anywhere.
__device__ __forceinline__ void lgkmbar() {
  asm volatile("s_waitcnt lgkmcnt(0)" ::: "memory");
  __builtin_amdgcn_s_barrier();
  __builtin_amdgcn_sched_barrier(0);
}

struct Taps { int n; unsigned dh2; unsigned dw2; };  // 2-bit packed (d+1); multi: 8 bits/class

// ---------------- MFMA implicit-GEMM conv: tile 128 px x 128 outch, K=taps*128 ----------------
// 8 waves / 512 threads per block: each wave owns 32px x 64outch -> acc only 32 AGPR,
// total regs ~100 <= 128 -> __launch_bounds__(512,4) = 2 blocks/CU = 16 waves/CU.
// (Round-4's 4-wave blocks left the ten 512-block dispatches at 8 waves/CU, latency-bound
// at 20% MfmaUtil with every throughput ceiling 4x away.)
// A: ONE reg set (8 VGPR), global->reg one chunk early, ds_write late, 2-buffer LDS (32KB),
//    XOR-swizzled store, conflict-free b128 reads. B: frag-major in regs, half-chunk recycle.
// One s_barrier per K=64 chunk, lgkmcnt(0) only (verified structure from round 4).
__global__ __launch_bounds__(512, 4) void conv_mfma(
    const u16* __restrict__ in, int inRS, int inIS, int si,
    const u16* __restrict__ wt, const float* __restrict__ bias, Taps tp,
    u16* __restrict__ out, int outRS, int outIS, int so, int oh0, int ow0,
    const u16* __restrict__ res, u16* __restrict__ out2, int reluMain,
    float* __restrict__ zeFc, u16* __restrict__ zeBFc, int multi)
{
  __shared__ u16 lA[2][8192];
  const int tid = threadIdx.x;
  const int w = tid >> 6, lane = tid & 63, quad = lane >> 4, l16 = lane & 15;
  const int wm = w >> 1, wn = w & 1;          // wm in [0,4): 32-px strip; wn: 64-outch half
  // XCD swizzle: gridDim.x == 512 always (512 % 8 == 0 -> bijective)
  const int bx = ((blockIdx.x & 7) << 6) | (blockIdx.x >> 3);
  const int blockM = bx << 7;

  unsigned dh2 = tp.dh2, dw2 = tp.dw2;
  if (multi) {
    const int cls = blockIdx.y;
    dh2 = (tp.dh2 >> (8*cls)) & 0xffu;
    dw2 = (tp.dw2 >> (8*cls)) & 0xffu;
    wt += cls << 16;
    oh0 = cls >> 1; ow0 = cls & 1;
  }

  // A staging: 512 threads x 2 x 16B = 16KB chunk. pixel row R = i*64 + (tid>>3),
  // global 16B chunk = tid&7 (linear), LDS col = (tid&7) ^ (R&7) (store-side swizzle).
  const int s = tid >> 3;                      // [0,64)
  const int swz = (tid & 7) ^ (s & 7);
  const int wOff = s*64 + swz*8;               // u16 units; +4096 for second row-set
  const int pg0 = blockM + s;
  const int b0 = pg0 >> 12, mo0 = (pg0 >> 6) & 63, no0 = pg0 & 63;
  const u16* gA0 = in + b0*inIS + si*mo0*inRS + si*no0*128 + (tid & 7)*8;
  const int gA1off = si*inRS;                  // rows 64..127 = mo0+1 (blockM 128-aligned)
  // B fragment pointer: frag-major layout [chunk ci][kk][row][quad][8]
  const u16* gBf = wt + (wn*64 + l16)*32 + quad*8;

  floatx4 zz = {0.f,0.f,0.f,0.f};
  floatx4 acc[2][4];
#pragma unroll
  for (int i=0;i<2;i++)
#pragma unroll
    for (int j=0;j<4;j++) acc[i][j] = zz;

  auto gloadA = [&](int ci, short8 (&a)[2]) {
    const int t = ci >> 1, kc = ci & 1;
    const int dh = (int)((dh2 >> (2*t)) & 3u) - 1;
    const int dw = (int)((dw2 >> (2*t)) & 3u) - 1;
    const int aoff = dh*inRS + dw*128 + kc*64;
    a[0] = *(const short8*)(gA0 + aoff);
    a[1] = *(const short8*)(gA0 + gA1off + aoff);
  };
  auto dswA = [&](u16* P, short8 (&a)[2]) {
    *(short8*)(P + wOff) = a[0];
    *(short8*)(P + 4096 + wOff) = a[1];
  };
  auto loadBk = [&](int ci, int kk, short8 (&v)[4]) {
    const u16* p = gBf + ci*8192 + kk*4096;
#pragma unroll
    for (int s4=0;s4<4;s4++) v[s4] = *(const short8*)(p + s4*512);
  };
  auto computeH = [&](const u16* P, int kk, short8 (&bfr)[4]) {
    short8 af[2];
#pragma unroll
    for (int ii=0;ii<2;ii++) {
      const int row = wm*32 + ii*16 + l16;
      af[ii] = *(const short8*)&P[row*64 + (((kk*4 + quad) ^ (l16 & 7)) << 3)];
    }
#pragma unroll
    for (int i=0;i<2;i++)
#pragma unroll
      for (int j=0;j<4;j++)
        acc[i][j] = __builtin_amdgcn_mfma_f32_16x16x32_bf16(af[i], bfr[j], acc[i][j], 0, 0, 0);
  };

  const int NCH = tp.n << 1;             // chunks of K=64 (>= 2)
  short8 a[2], bA[4], bB[4];
  // prologue: stage chunk 0, prefetch A(1)
  gloadA(0, a);
  loadBk(0, 0, bA);
  loadBk(0, 1, bB);
  dswA(&lA[0][0], a);                    // waits on a's global loads (register dep)
  gloadA(1, a);                          // prefetch A(1); rides across the barrier
  lgkmbar();

  int cur = 0;
  for (int ci = 0; ci < NCH; ++ci) {
    computeH(&lA[cur][0], 0, bA);
    if (ci + 1 < NCH) loadBk(ci + 1, 0, bA);   // recycle bA after kk=0 consumed it
    computeH(&lA[cur][0], 1, bB);
    if (ci + 1 < NCH) {
      loadBk(ci + 1, 1, bB);             // recycle bB after kk=1 consumed it
      dswA(&lA[cur ^ 1][0], a);          // write-late: A(ci+1) into the other buffer
      if (ci + 2 < NCH) gloadA(ci + 2, a);
      lgkmbar();                         // own ds_writes drained; buffer safe next chunk
    }
    cur ^= 1;
  }

  float bv[4];
#pragma unroll
  for (int j=0;j<4;j++) bv[j] = bias[wn*64 + j*16 + l16];

#pragma unroll
  for (int i=0;i<2;i++) {
#pragma unroll
    for (int r=0;r<4;r++) {
      const int p = blockM + wm*32 + i*16 + quad*4 + r;
      const int bb2 = p >> 12, mo = (p >> 6) & 63, no = p & 63;
      const int ob = bb2*outIS + (so*mo + oh0)*outRS + (so*no + ow0)*128;
#pragma unroll
      for (int j=0;j<4;j++) {
        const int n = wn*64 + j*16 + l16;
        float v = acc[i][j][r] + bv[j];
        if (res)  v += bf2f(res[ob + n]);
        if (out)  out[ob + n]  = f2bf(reluMain ? fmaxf(v, 0.f) : v);
        if (out2) out2[ob + n] = f2bf(fmaxf(v, 0.f));
        if (zeFc) {
          zeFc[((size_t)p << 7) + n] = v;          // compact fp32 (coalesced)
          zeBFc[((size_t)p << 7) + n] = f2bf(v);   // compact bf16 for VQ
        }
      }
    }
  }
}

// ---------------- VQ: scores = ze . cb^T, per-pixel argmin via packed atomicMin ----------------
// Same 8-wave slim pipeline (NCH == 2 unrolled).
__global__ __launch_bounds__(512, 4) void vq_score(
    const u16* __restrict__ zeBF, const u16* __restrict__ cbF,
    const float* __restrict__ cbn, unsigned long long* __restrict__ minbuf)
{
  __shared__ u16 lA[2][8192];
  const int tid = threadIdx.x;
  const int w = tid >> 6, lane = tid & 63, quad = lane >> 4, l16 = lane & 15;
  const int wm = w >> 1, wn = w & 1;
  const int bx = ((blockIdx.x & 7) << 6) | (blockIdx.x >> 3);
  const int blockM = bx << 7;
  const int nb = blockIdx.y;
  const int s = tid >> 3;
  const int swz = (tid & 7) ^ (s & 7);
  const int wOff = s*64 + swz*8;
  const u16* gA0 = zeBF + ((size_t)(blockM + s) << 7) + (tid & 7)*8;
  const int gA1off = 64 << 7;
  const u16* gBf = cbF + (nb << 14) + (wn*64 + l16)*32 + quad*8;

  floatx4 zz = {0.f,0.f,0.f,0.f};
  floatx4 acc[2][4];
#pragma unroll
  for (int i=0;i<2;i++)
#pragma unroll
    for (int j=0;j<4;j++) acc[i][j] = zz;

  auto gloadA = [&](int ci, short8 (&a)[2]) {
    a[0] = *(const short8*)(gA0 + ci*64);
    a[1] = *(const short8*)(gA0 + gA1off + ci*64);
  };
  auto dswA = [&](u16* P, short8 (&a)[2]) {
    *(short8*)(P + wOff) = a[0];
    *(short8*)(P + 4096 + wOff) = a[1];
  };
  auto loadBk = [&](int ci, int kk, short8 (&v)[4]) {
    const u16* p = gBf + ci*8192 + kk*4096;
#pragma unroll
    for (int s4=0;s4<4;s4++) v[s4] = *(const short8*)(p + s4*512);
  };
  auto computeH = [&](const u16* P, int kk, short8 (&bfr)[4]) {
    short8 af[2];
#pragma unroll
    for (int ii=0;ii<2;ii++) {
      const int row = wm*32 + ii*16 + l16;
      af[ii] = *(const short8*)&P[row*64 + (((kk*4 + quad) ^ (l16 & 7)) << 3)];
    }
#pragma unroll
    for (int i=0;i<2;i++)
#pragma unroll
      for (int j=0;j<4;j++)
        acc[i][j] = __builtin_amdgcn_mfma_f32_16x16x32_bf16(af[i], bfr[j], acc[i][j], 0, 0, 0);
  };

  short8 a[2], bA[4], bB[4];
  gloadA(0, a);
  loadBk(0, 0, bA);
  loadBk(0, 1, bB);
  dswA(&lA[0][0], a);
  gloadA(1, a);
  lgkmbar();
  computeH(&lA[0][0], 0, bA);
  loadBk(1, 0, bA);
  computeH(&lA[0][0], 1, bB);
  loadBk(1, 1, bB);
  dswA(&lA[1][0], a);
  lgkmbar();
  computeH(&lA[1][0], 0, bA);
  computeH(&lA[1][0], 1, bB);

  float cn[4];
#pragma unroll
  for (int j=0;j<4;j++) cn[j] = cbn[nb*128 + wn*64 + j*16 + l16];

#pragma unroll
  for (int i=0;i<2;i++) {
#pragma unroll
    for (int r=0;r<4;r++) {
      const int p = blockM + wm*32 + i*16 + quad*4 + r;
      unsigned long long best = 0xFFFFFFFFFFFFFFFFull;
#pragma unroll
      for (int j=0;j<4;j++) {
        const int n = nb*128 + wn*64 + j*16 + l16;
        float v = cn[j] - acc[i][j][r];       // 0.5||e||^2 - z.e  (same argmin as L2 dist)
        unsigned long long pk = ((unsigned long long)fkey(v) << 32) | (unsigned)n;
        if (pk < best) best = pk;
      }
#pragma unroll
      for (int d=1; d<16; d<<=1) {
        unsigned long long o = __shfl_xor(best, d, 64);
        if (o < best) best = o;
      }
      if (l16 == 0) atomicMin(minbuf + p, best);
    }
  }
}

// ---------------- finalize: ze transpose -> NCHW, zq gather -> NCHW + bf16 NHWC, coalesced ----------------
__global__ __launch_bounds__(256) void finalize(
    const float* __restrict__ zeFc, const unsigned long long* __restrict__ minb,
    const float* __restrict__ cb, float* __restrict__ outZe, float* __restrict__ outZq,
    u16* __restrict__ zqI)
{
  __shared__ float T[64*129];
  __shared__ int ns[64];
  const int tid = threadIdx.x;
  const int P0 = blockIdx.x << 6;                 // 64 pixels, same image & h-row
  const int b = P0 >> 12, hw0 = P0 & 4095;

#pragma unroll
  for (int it=0; it<32; ++it) {                   // coalesced read of ze tile
    int e = it*256 + tid;
    int px = e >> 7, c = e & 127;
    T[px*129 + c] = zeFc[((size_t)P0 << 7) + e];
  }
  if (tid < 64) ns[tid] = (int)(unsigned)(minb[P0 + tid] & 0xFFFFFFFFull);
  __syncthreads();

  float* zeB = outZe + (((size_t)b) << 19) + hw0;
  float* zqB = outZq + (((size_t)b) << 19) + hw0;
  const int h = hw0 >> 6;
  u16* zqIB = zqI + b*IS66 + h*RS66;
#pragma unroll
  for (int it=0; it<32; ++it) {
    const int c = it*4 + (tid >> 6);
    const int px = tid & 63;
    zeB[(c << 12) + px] = T[px*129 + c];
    float v = cb[(ns[px] << 7) + c];
    zqB[(c << 12) + px] = v;
    zqIB[px*128 + c] = f2bf(v);
  }
}

// ---------------- zero halos + init VQ argmin buffer ----------------
__global__ __launch_bounds__(256) void zero_halos(
    u16* big, u16* s0, u16* s1, u16* s2, u16* s3, unsigned long long* minb)
{
  int id = blockIdx.x*256 + threadIdx.x;
  if (id >= 463872) return;
  if (id >= 398336) { minb[id - 398336] = 0xFFFFFFFFFFFFFFFFull; return; }
  u16* base; int H, W;
  if (id < 132096) { base = big; H = 128; W = 128; }
  else {
    id -= 132096;
    int bi = id / 66560;
    id -= bi*66560;
    base = (bi == 0) ? s0 : (bi == 1) ? s1 : (bi == 2) ? s2 : s3;
    H = 64; W = 64;
  }
  int Wp = W+2, Hp = H+2;
  int cv = id & 15; int rest = id >> 4;
  int npx = 2*Wp + 2*H;
  int img = rest / npx; int pix = rest - img*npx;
  int hh, wwp;
  if (pix < Wp) { hh = 0; wwp = pix; }
  else if (pix < 2*Wp) { hh = Hp-1; wwp = pix - Wp; }
  else { int r2 = pix - 2*Wp; hh = 1 + (r2 >> 1); wwp = (r2 & 1) ? (Wp-1) : 0; }
  uint4 zv = {0u,0u,0u,0u};
  *(uint4*)(base + (((size_t)img*Hp + hh)*Wp + wwp)*128 + cv*8) = zv;
}

// ---------------- weight prep ----------------
struct WEnt { const float* src; u16* dst; int O, I, T, mode; };
struct WTab { int n; WEnt e[16]; int cum[17]; };
__global__ __launch_bounds__(256) void prep_w(WTab wt) {
  int id = blockIdx.x*256 + threadIdx.x;
  if (id >= wt.cum[wt.n]) return;
  int k = 0;
  while (id >= wt.cum[k+1]) k++;
  int l = id - wt.cum[k];
  WEnt E = wt.e[k];
  if (E.mode == 6) {                        // frag-major conv weights [O=128][I=128] x T taps
    int e = l & 7, quad = (l >> 3) & 3, row = (l >> 5) & 127;
    int kk = (l >> 12) & 1, kc = (l >> 13) & 1, t = l >> 14;
    int i = kc*64 + kk*32 + quad*8 + e;
    E.dst[l] = f2bf(E.src[(row*E.I + i)*E.T + t]);
  } else if (E.mode == 1) {                 // convT dt1 frag-major: [cls][tap][...]
    int e = l & 7, quad = (l >> 3) & 3, row = (l >> 5) & 127;
    int kk = (l >> 12) & 1, kc = (l >> 13) & 1, tt = (l >> 14) & 3, cls = l >> 16;
    int i = kc*64 + kk*32 + quad*8 + e;
    int th = tt >> 1, tw = tt & 1, po = cls >> 1, pw = cls & 1;
    int kh = po ? (th ? 2 : 0) : (th ? 3 : 1);
    int kw = pw ? (tw ? 2 : 0) : (tw ? 3 : 1);
    E.dst[l] = f2bf(E.src[((i*128 + row)*4 + kh)*4 + kw]);
  } else if (E.mode == 7) {                 // frag-major codebook [512][128] -> 4 row-tiles
    int e = l & 7, quad = (l >> 3) & 3, row = (l >> 5) & 127;
    int kk = (l >> 12) & 1, kc = (l >> 13) & 1, tt = l >> 14;
    int i = kc*64 + kk*32 + quad*8 + e;
    E.dst[l] = f2bf(E.src[(tt*128 + row)*128 + i]);
  } else if (E.mode == 3) {                 // codebook 0.5*||e||^2
    float s = 0.f; const float* r = E.src + l*128;
    for (int c=0;c<128;c++) s += r[c]*r[c];
    ((float*)E.dst)[l] = 0.5f*s;
  } else if (E.mode == 4) {                 // e1 weights fp32 [o][48] -> [tap][o]
    int o = l & 127, tap = l >> 7;
    ((float*)E.dst)[l] = E.src[o*48 + tap];
  } else {                                  // mode 5: dt2 [c128][o3][4][4] -> bf16 [n48][c128]
    int c = l & 127, n = l >> 7;            // n = o*16 + kh*4+kw
    int o = n >> 4, kk = n & 15;
    E.dst[l] = f2bf(E.src[c*48 + o*16 + kk]);
  }
}

// ---------------- e1: 3->128, k4 s2 p1, row-tiled direct fp32, relu -> bf16 NHWC halo ----------------
__global__ __launch_bounds__(256) void conv_e1(
    const float* __restrict__ x, const float* __restrict__ wT,   // wT: [tap48][o128] fp32
    const float* __restrict__ bias, u16* __restrict__ outI)
{
  __shared__ float inS[12*260];
  __shared__ float wS[48*128];
  __shared__ float bS[128];
  const int tid = threadIdx.x;
  const int b = blockIdx.x >> 7, ho = blockIdx.x & 127;

  for (int l = tid; l < 1536; l += 256)
    ((float4*)wS)[l] = ((const float4*)wT)[l];
  if (tid < 128) bS[tid] = bias[tid];
  for (int l = tid; l < 3120; l += 256) {
    int col = l % 260; int rest = l / 260;
    int kh = rest & 3, c = rest >> 2;
    int hi = 2*ho + kh - 1, wi = col - 1;
    float v = 0.f;
    if ((unsigned)hi < 256u && (unsigned)wi < 256u)
      v = x[((b*3 + c) << 16) + (hi << 8) + wi];
    inS[rest*260 + col] = v;
  }
  __syncthreads();

  const int g = tid & 7;
  const int pxg = tid >> 3;
  floatx4 acc[4][4];
  {
    const floatx4* bp = (const floatx4*)&bS[g*16];
    floatx4 b0 = bp[0], b1 = bp[1], b2 = bp[2], b3 = bp[3];
#pragma unroll
    for (int px=0;px<4;px++) { acc[px][0]=b0; acc[px][1]=b1; acc[px][2]=b2; acc[px][3]=b3; }
  }
#pragma unroll
  for (int c=0;c<3;c++)
#pragma unroll
    for (int kh=0;kh<4;kh++) {
      const float* row = &inS[(c*4+kh)*260];
#pragma unroll
      for (int kw=0;kw<4;kw++) {
        const int tap = c*16 + kh*4 + kw;
        const floatx4* wp = (const floatx4*)&wS[tap*128 + g*16];
        floatx4 w0 = wp[0], w1 = wp[1], w2 = wp[2], w3 = wp[3];
#pragma unroll
        for (int px=0;px<4;px++) {
          float xv = row[((pxg*4 + px) << 1) + kw];
          acc[px][0] += xv*w0; acc[px][1] += xv*w1;
          acc[px][2] += xv*w2; acc[px][3] += xv*w3;
        }
      }
    }

  u16* ob = outI + b*IS130 + ho*RS130;
#pragma unroll
  for (int px=0;px<4;px++) {
    const int wo = pxg*4 + px;
    u16* p = ob + wo*128 + g*16;
#pragma unroll
    for (int k=0;k<4;k++) {
      union { u16 u[4]; uint2 v2; } pk;
#pragma unroll
      for (int j=0;j<4;j++) pk.u[j] = f2bf(fmaxf(acc[px][k][j], 0.f));
      *(uint2*)(p + k*4) = pk.v2;
    }
  }
}

// ---------------- dt2 GEMM: cols[p][48] = in[p][128ch] . Wb[48][128]^T, MFMA, no LDS ----------------
__global__ __launch_bounds__(256) void dt2_gemm(
    const u16* __restrict__ inI, const u16* __restrict__ Wb,
    float* __restrict__ cols)
{
  const int tid = threadIdx.x;
  const int w = tid >> 6, lane = tid & 63, quad = lane >> 4, l16 = lane & 15;
  const int pixBase = blockIdx.x*256 + w*64;

  short8 Bf[3][4];
#pragma unroll
  for (int nt=0; nt<3; nt++)
#pragma unroll
    for (int kc=0; kc<4; kc++)
      Bf[nt][kc] = *(const short8*)(Wb + (nt*16 + l16)*128 + kc*32 + quad*8);

  const u16* ap[4];
#pragma unroll
  for (int ms=0; ms<4; ms++) {
    int p = pixBase + ms*16 + l16;
    int b = p >> 14, rem = p & 16383;
    ap[ms] = inI + b*IS130 + (rem >> 7)*RS130 + (rem & 127)*128;
  }

  floatx4 zz = {0.f,0.f,0.f,0.f};
  floatx4 acc[4][3];
#pragma unroll
  for (int ms=0; ms<4; ms++)
#pragma unroll
    for (int nt=0; nt<3; nt++) acc[ms][nt] = zz;

#pragma unroll
  for (int kc=0; kc<4; kc++) {
#pragma unroll
    for (int ms=0; ms<4; ms++) {
      short8 a = *(const short8*)(ap[ms] + kc*32 + quad*8);
#pragma unroll
      for (int nt=0; nt<3; nt++)
        acc[ms][nt] = __builtin_amdgcn_mfma_f32_16x16x32_bf16(a, Bf[nt][kc], acc[ms][nt], 0, 0, 0);
    }
  }

#pragma unroll
  for (int ms=0; ms<4; ms++)
#pragma unroll
    for (int nt=0; nt<3; nt++)
#pragma unroll
      for (int r=0; r<4; r++) {
        int p = pixBase + ms*16 + quad*4 + r;
        cols[(size_t)p*48 + nt*16 + l16] = acc[ms][nt][r];
      }
}

// ---------------- dt2 gather: col2im + bias -> NCHW fp32 ----------------
__global__ __launch_bounds__(256) void dt2_gather(
    const float* __restrict__ cols, const float* __restrict__ bias,
    float* __restrict__ xhat)
{
  int id = blockIdx.x*256 + threadIdx.x;
  int b = id >> 16, rem = id & 65535;
  int ho = rem >> 8, wo = rem & 255;
  const int ph = ho & 1, pw = wo & 1;
  const int hi0 = ph ? ((ho+1)>>1) : (ho>>1);
  const int kh0 = ph ? 0 : 1;
  const int wi0 = pw ? ((wo+1)>>1) : (wo>>1);
  const int kw0 = pw ? 0 : 1;
  float a0 = bias[0], a1 = bias[1], a2 = bias[2];
#pragma unroll
  for (int th=0; th<2; th++) {
    const int hi = hi0 - th;
    if ((unsigned)hi >= 128u) continue;
    const int kh = kh0 + 2*th;
#pragma unroll
    for (int tw=0; tw<2; tw++) {
      const int wi = wi0 - tw;
      if ((unsigned)wi >= 128u) continue;
      const int kw = kw0 + 2*tw;
      const float* r = cols + (size_t)((b << 14) + (hi << 7) + wi)*48 + (kh*4 + kw);
      a0 += r[0]; a1 += r[16]; a2 += r[32];
    }
  }
  const int ob = ((b*3) << 16) + (ho << 8) + wo;
  xhat[ob]          = a0;
  xhat[ob + 65536]  = a1;
  xhat[ob + 131072] = a2;
}

// =====================================================================================
extern "C" void kernel_launch(void* const* d_in, const int* in_sizes, int n_in,
                              void* d_out, int out_size, void* d_ws, size_t ws_size,
                              hipStream_t stream)
{
  const float* x     = (const float*)d_in[0];
  const float* e1w   = (const float*)d_in[1];
  const float* e1b   = (const float*)d_in[2];
  const float* e2w   = (const float*)d_in[3];
  const float* e2b   = (const float*)d_in[4];
  const float* e3w   = (const float*)d_in[5];
  const float* e3b   = (const float*)d_in[6];
  const float* er1aw = (const float*)d_in[7];
  const float* er1ab = (const float*)d_in[8];
  const float* er1bw = (const float*)d_in[9];
  const float* er1bb = (const float*)d_in[10];
  const float* er2aw = (const float*)d_in[11];
  const float* er2ab = (const float*)d_in[12];
  const float* er2bw = (const float*)d_in[13];
  const float* er2bb = (const float*)d_in[14];
  const float* cb    = (const float*)d_in[15];
  const float* d1w   = (const float*)d_in[16];
  const float* d1b   = (const float*)d_in[17];
  const float* dr1aw = (const float*)d_in[18];
  const float* dr1ab = (const float*)d_in[19];
  const float* dr1bw = (const float*)d_in[20];
  const float* dr1bb = (const float*)d_in[21];
  const float* dr2aw = (const float*)d_in[22];
  const float* dr2ab = (const float*)d_in[23];
  const float* dr2bw = (const float*)d_in[24];
  const float* dr2bb = (const float*)d_in[25];
  const float* dt1w  = (const float*)d_in[26];
  const float* dt1b  = (const float*)d_in[27];
  const float* dt2w  = (const float*)d_in[28];
  const float* dt2b  = (const float*)d_in[29];
  float* out = (float*)d_out;

  char* ws = (char*)d_ws;
  size_t off = 0;
  auto alloc = [&](size_t bytes) -> void* {
    void* r = ws + off; off += (bytes + 255) & ~(size_t)255; return r;
  };

  u16* BIG = (u16*)alloc((size_t)IS130*16*2);      // e1-out / ze-compact / dt1-out
  u16* S[4];
  for (int i=0;i<4;i++) S[i] = (u16*)alloc((size_t)IS66*16*2);
  unsigned long long* minb = (unsigned long long*)alloc((size_t)65536*8);
  u16* W_e2 = (u16*)alloc(262144*2);
  u16* W9[6]; for (int i=0;i<6;i++) W9[i] = (u16*)alloc(147456*2);
  u16* W1[4]; for (int i=0;i<4;i++) W1[i] = (u16*)alloc(16384*2);
  u16* Wdt1 = (u16*)alloc(262144*2);
  u16* cbBF = (u16*)alloc(65536*2);
  float* cbn = (float*)alloc(512*4);
  float* wsE1 = (float*)alloc(6144*4);
  u16* Wb48 = (u16*)alloc(6144*2);

  u16* BIGi = BIG + RS130 + 128;
  u16* Si[4];
  for (int i=0;i<4;i++) Si[i] = S[i] + RS66 + 128;
  u16* zeBFc = S[1];            // compact bf16 ze (VQ A-matrix), S1 dead by er2b
  float* zeFc = (float*)BIG;    // compact fp32 ze (32MB) — BIG free between e2 and dt1
  float* cols = (float*)S[1];   // dt2 cols fp32 spans S1..S3 (dead by dt2 time)

  // 1. zero halos + init minb
  zero_halos<<<1812, 256, 0, stream>>>(BIG, S[0], S[1], S[2], S[3], minb);

  // 2. weights
  WTab wtab; int ne = 0; wtab.cum[0] = 0;
  auto addw = [&](const float* s, u16* d, int O, int I, int T, int m, int items) {
    wtab.e[ne] = {s, d, O, I, T, m};
    wtab.cum[ne+1] = wtab.cum[ne] + items; ne++;
  };
  addw(e2w,   W_e2, 128,128,16,6, 262144);
  addw(e3w,   W9[0],128,128, 9,6, 147456);
  addw(er1aw, W9[1],128,128, 9,6, 147456);
  addw(er2aw, W9[2],128,128, 9,6, 147456);
  addw(d1w,   W9[3],128,128, 9,6, 147456);
  addw(dr1aw, W9[4],128,128, 9,6, 147456);
  addw(dr2aw, W9[5],128,128, 9,6, 147456);
  addw(er1bw, W1[0],128,128, 1,6, 16384);
  addw(er2bw, W1[1],128,128, 1,6, 16384);
  addw(dr1bw, W1[2],128,128, 1,6, 16384);
  addw(dr2bw, W1[3],128,128, 1,6, 16384);
  addw(dt1w,  Wdt1, 0,0,0,1, 262144);
  addw(cb,    cbBF, 0,0,0,7, 65536);
  addw(cb,    (u16*)cbn, 0,0,0,3, 512);
  addw(e1w,   (u16*)wsE1, 0,0,0,4, 6144);
  addw(dt2w,  Wb48, 0,0,0,5, 6144);
  wtab.n = ne;
  prep_w<<<(wtab.cum[ne] + 255)/256, 256, 0, stream>>>(wtab);

  // 3. e1
  conv_e1<<<2048, 256, 0, stream>>>(x, wsE1, e1b, BIGi);

  // taps
  Taps t16; t16.n = 16; t16.dh2 = 0; t16.dw2 = 0;
  for (int t=0;t<16;t++) { t16.dh2 |= (unsigned)(t>>2) << (2*t); t16.dw2 |= (unsigned)(t&3) << (2*t); }
  Taps t9; t9.n = 9; t9.dh2 = 0; t9.dw2 = 0;
  for (int t=0;t<9;t++) { t9.dh2 |= (unsigned)(t/3) << (2*t); t9.dw2 |= (unsigned)(t%3) << (2*t); }
  Taps t1x; t1x.n = 1; t1x.dh2 = 1; t1x.dw2 = 1;
  Taps tcm; tcm.n = 4; tcm.dh2 = 0; tcm.dw2 = 0;   // packed: 8 bits per class
  for (int cls=0; cls<4; ++cls) {
    int po = cls >> 1, pw = cls & 1;
    for (int tt=0; tt<4; ++tt) {
      int th = tt >> 1, tw = tt & 1;
      int dh = po ? (th ? 0 : 1) : (th ? -1 : 0);
      int dw = pw ? (tw ? 0 : 1) : (tw ? -1 : 0);
      tcm.dh2 |= (unsigned)(dh+1) << (8*cls + 2*tt);
      tcm.dw2 |= (unsigned)(dw+1) << (8*cls + 2*tt);
    }
  }

  auto conv = [&](const u16* in_, int iRS, int iIS, int si,
                  const u16* w_, const float* b_, Taps tp,
                  u16* o_, int oRS, int oIS, int so, int oh, int ow,
                  const u16* r_, u16* o2, int rl, float* zf, u16* zb) {
    conv_mfma<<<512, 512, 0, stream>>>(in_, iRS, iIS, si, w_, b_, tp,
                                       o_, oRS, oIS, so, oh, ow, r_, o2, rl, zf, zb, 0);
  };

  // encoder
  conv(BIGi, RS130, IS130, 2, W_e2, e2b, t16, Si[0], RS66, IS66, 1,0,0, nullptr, nullptr, 1, nullptr, nullptr); // e2 -> S0 (relu)
  conv(Si[0], RS66, IS66, 1, W9[0], e3b, t9, Si[1], RS66, IS66, 1,0,0, nullptr, Si[2], 0, nullptr, nullptr);    // e3 -> t2=S1, relu->S2
  conv(Si[2], RS66, IS66, 1, W9[1], er1ab, t9, Si[0], RS66, IS66, 1,0,0, nullptr, nullptr, 1, nullptr, nullptr);// er1a -> S0 (relu)
  conv(Si[0], RS66, IS66, 1, W1[0], er1bb, t1x, Si[3], RS66, IS66, 1,0,0, Si[1], Si[2], 0, nullptr, nullptr);   // er1b(+t2) -> t4=S3, relu->S2
  conv(Si[2], RS66, IS66, 1, W9[2], er2ab, t9, Si[0], RS66, IS66, 1,0,0, nullptr, nullptr, 1, nullptr, nullptr);// er2a -> S0 (relu)
  conv(Si[0], RS66, IS66, 1, W1[1], er2bb, t1x, nullptr, RS66, IS66, 1,0,0, Si[3], nullptr, 0, zeFc, zeBFc);    // er2b(+t4) -> ze compact (fp32+bf16)

  // VQ + outputs
  vq_score<<<dim3(512,4), 512, 0, stream>>>(zeBFc, cbBF, cbn, minb);
  finalize<<<1024, 256, 0, stream>>>(zeFc, minb, cb, out + 3145728, out + 11534336, Si[2]);  // zq bf16 -> S2

  // decoder
  conv(Si[2], RS66, IS66, 1, W9[3], d1b, t9, Si[0], RS66, IS66, 1,0,0, nullptr, Si[1], 0, nullptr, nullptr);    // d1 -> g1=S0, relu->S1
  conv(Si[1], RS66, IS66, 1, W9[4], dr1ab, t9, Si[2], RS66, IS66, 1,0,0, nullptr, nullptr, 1, nullptr, nullptr);// dr1a -> S2 (relu)
  conv(Si[2], RS66, IS66, 1, W1[2], dr1bb, t1x, Si[3], RS66, IS66, 1,0,0, Si[0], Si[1], 0, nullptr, nullptr);   // dr1b(+g1) -> g2=S3, relu->S1
  conv(Si[1], RS66, IS66, 1, W9[5], dr2ab, t9, Si[2], RS66, IS66, 1,0,0, nullptr, nullptr, 1, nullptr, nullptr);// dr2a -> S2 (relu)
  conv(Si[2], RS66, IS66, 1, W1[3], dr2bb, t1x, Si[0], RS66, IS66, 1,0,0, Si[3], nullptr, 0, nullptr, nullptr); // dr2b(+g2) -> g3=S0

  // dt1: 4 parity classes in one dispatch (blockIdx.y = cls)
  conv_mfma<<<dim3(512,4), 512, 0, stream>>>(Si[0], RS66, IS66, 1, Wdt1, dt1b, tcm,
                                             BIGi, RS130, IS130, 2, 0, 0,
                                             nullptr, nullptr, 1, nullptr, nullptr, 1);

  // dt2: cols GEMM (MFMA) + col2im gather
  dt2_gemm<<<1024, 256, 0, stream>>>(BIGi, Wb48, cols);
  dt2_gather<<<4096, 256, 0, stream>>>(cols, dt2b, out);
}

// Round 6
// 782.796 us; speedup vs baseline: 1.0479x; 1.0479x over previous
//
#include <hip/hip_runtime.h>
#include <stdint.h>

typedef unsigned short u16;
typedef __attribute__((ext_vector_type(8))) short short8;
typedef __attribute__((ext_vector_type(4))) float floatx4;

#define RS66  (66*128)
#define IS66  (66*66*128)
#define RS130 (130*128)
#define IS130 (130*130*128)

__device__ __forceinline__ float bf2f(u16 h) {
  union { unsigned u; float f; } v; v.u = ((unsigned)h) << 16; return v.f;
}
__device__ __forceinline__ u16 f2bf(float f) {
  union { float f; unsigned u; } v; v.f = f;
  unsigned r = v.u + 0x7FFFu + ((v.u >> 16) & 1u);
  return (u16)(r >> 16);
}
__device__ __forceinline__ unsigned fkey(float f) {
  unsigned u = __float_as_uint(f);
  return (u & 0x80000000u) ? ~u : (u | 0x80000000u);
}
// LDS-visibility barrier: drain own ds ops (lgkmcnt), then join. Global loads
// (register-destined) ride across freely; their waits are compiler-managed via
// real register dependencies. No manual vmcnt anywhere.
__device__ __forceinline__ void lgkmbar() {
  asm volatile("s_waitcnt lgkmcnt(0)" ::: "memory");
  __builtin_amdgcn_s_barrier();
  __builtin_amdgcn_sched_barrier(0);
}

struct Taps { int n; unsigned dh2; unsigned dw2; };  // 2-bit packed (d+1); multi: 8 bits/class

// ---------------- MFMA implicit-GEMM conv: tile 128 px x 128 outch, K=taps*128 ----------------
// BK=128 (one full tap per chunk): halves barrier count vs BK=64 and doubles per-chunk
// MFMA cover (64 MFMA/wave between barriers) -- attacks the measured per-barrier serial
// stall (R5 showed MORE waves with SHORTER chunks is worse; so go the other way).
// A: one reg set a[8] (32 VGPR), loaded one chunk early, ds_write late, 2x32KB LDS buffers,
//    XOR-swizzled store, conflict-free b128 reads (same swizzle family as R4, measured 0 conflicts).
// B: L2-resident frag-major, two reg sets ping-ponged at kk (K=32) granularity.
// launch_bounds(256,2): VGPR cap 256 -> no spill possible; 2 blocks/CU (64KB LDS each).
__global__ __launch_bounds__(256, 2) void conv_mfma(
    const u16* __restrict__ in, int inRS, int inIS, int si,
    const u16* __restrict__ wt, const float* __restrict__ bias, Taps tp,
    u16* __restrict__ out, int outRS, int outIS, int so, int oh0, int ow0,
    const u16* __restrict__ res, u16* __restrict__ out2, int reluMain,
    float* __restrict__ zeFc, u16* __restrict__ zeBFc, int multi)
{
  __shared__ u16 lA[2][16384];
  const int tid = threadIdx.x;
  const int w = tid >> 6, lane = tid & 63, quad = lane >> 4, l16 = lane & 15;
  const int wm = w >> 1, wn = w & 1;
  // XCD swizzle: gridDim.x == 512 always (512 % 8 == 0 -> bijective)
  const int bx = ((blockIdx.x & 7) << 6) | (blockIdx.x >> 3);
  const int blockM = bx << 7;

  unsigned dh2 = tp.dh2, dw2 = tp.dw2;
  if (multi) {
    const int cls = blockIdx.y;
    dh2 = (tp.dh2 >> (8*cls)) & 0xffu;
    dw2 = (tp.dw2 >> (8*cls)) & 0xffu;
    wt += cls << 16;
    oh0 = cls >> 1; ow0 = cls & 1;
  }

  // A staging (32KB chunk = 128px x 128K u16): thread covers px = i*32 + (tid>>3), i=0..3,
  // and 16B K-chunks c = h*8 + (tid&7), h=0..1. Global read linear; LDS col = c ^ (px&7)
  // (store-side XOR swizzle, low-3 bits only so the h-half is preserved).
  const int swz3 = (tid & 7) ^ ((tid >> 3) & 7);
  const int wBase = (tid >> 3)*128 + swz3*8;   // u16 units; + i*4096 + h*64
  const u16* gA[4];
#pragma unroll
  for (int i=0;i<4;i++) {
    const int pg = blockM + i*32 + (tid >> 3);
    const int b = pg >> 12, mo = (pg >> 6) & 63, no = pg & 63;
    gA[i] = in + b*inIS + si*mo*inRS + si*no*128 + (tid & 7)*8;
  }
  // B fragment pointer: frag-major layout [tap ci][kk 0..3][row 128][quad][8]
  const u16* gBf = wt + (wn*64 + l16)*32 + quad*8;

  floatx4 zz = {0.f,0.f,0.f,0.f};
  floatx4 acc[4][4];
#pragma unroll
  for (int i=0;i<4;i++)
#pragma unroll
    for (int j=0;j<4;j++) acc[i][j] = zz;

  auto gloadA = [&](int t, short8 (&a)[8]) {
    const int dh = (int)((dh2 >> (2*t)) & 3u) - 1;
    const int dw = (int)((dw2 >> (2*t)) & 3u) - 1;
    const int aoff = dh*inRS + dw*128;
#pragma unroll
    for (int i=0;i<4;i++)
#pragma unroll
      for (int h=0;h<2;h++)
        a[i*2+h] = *(const short8*)(gA[i] + aoff + h*64);
  };
  auto dswA = [&](u16* P, short8 (&a)[8]) {
#pragma unroll
    for (int i=0;i<4;i++)
#pragma unroll
      for (int h=0;h<2;h++)
        *(short8*)(P + i*4096 + wBase + h*64) = a[i*2+h];
  };
  auto loadBk = [&](int ci, int kk, short8 (&v)[4]) {
    const u16* p = gBf + ci*16384 + kk*4096;
#pragma unroll
    for (int s4=0;s4<4;s4++) v[s4] = *(const short8*)(p + s4*512);
  };
  auto computeH = [&](const u16* P, int kk, short8 (&bfr)[4]) {
    short8 af[4];
#pragma unroll
    for (int s4=0;s4<4;s4++) {
      const int row = wm*64 + s4*16 + l16;
      af[s4] = *(const short8*)&P[row*128 + (((kk*4 + quad) ^ (l16 & 7)) << 3)];
    }
#pragma unroll
    for (int i=0;i<4;i++)
#pragma unroll
      for (int j=0;j<4;j++)
        acc[i][j] = __builtin_amdgcn_mfma_f32_16x16x32_bf16(af[i], bfr[j], acc[i][j], 0, 0, 0);
  };

  const int NCH = tp.n;                  // chunks of K=128 (one tap each), >= 1
  short8 a[8], bA[4], bB[4];
  // prologue: stage chunk 0, prefetch A(1)
  gloadA(0, a);
  loadBk(0, 0, bA);
  dswA(&lA[0][0], a);                    // waits on a's global loads (register dep)
  if (NCH > 1) gloadA(1, a);             // prefetch; rides across the barrier
  lgkmbar();

  int cur = 0;
  for (int ci = 0; ci < NCH; ++ci) {
    loadBk(ci, 1, bB);
    computeH(&lA[cur][0], 0, bA);
    loadBk(ci, 2, bA);                   // recycle bA after kk=0 consumed it
    computeH(&lA[cur][0], 1, bB);
    loadBk(ci, 3, bB);
    computeH(&lA[cur][0], 2, bA);
    if (ci + 1 < NCH) {
      loadBk(ci + 1, 0, bA);
      dswA(&lA[cur ^ 1][0], a);          // write-late: A(ci+1) into the other buffer
      if (ci + 2 < NCH) gloadA(ci + 2, a);
    }
    computeH(&lA[cur][0], 3, bB);        // overlaps the ds_writes above
    if (ci + 1 < NCH) lgkmbar();         // own ds ops drained; buffer safe next chunk
    cur ^= 1;
  }

  float bv[4];
#pragma unroll
  for (int j=0;j<4;j++) bv[j] = bias[wn*64 + j*16 + l16];

#pragma unroll
  for (int i=0;i<4;i++) {
#pragma unroll
    for (int r=0;r<4;r++) {
      const int p = blockM + wm*64 + i*16 + quad*4 + r;
      const int bb2 = p >> 12, mo = (p >> 6) & 63, no = p & 63;
      const int ob = bb2*outIS + (so*mo + oh0)*outRS + (so*no + ow0)*128;
#pragma unroll
      for (int j=0;j<4;j++) {
        const int n = wn*64 + j*16 + l16;
        float v = acc[i][j][r] + bv[j];
        if (res)  v += bf2f(res[ob + n]);
        if (out)  out[ob + n]  = f2bf(reluMain ? fmaxf(v, 0.f) : v);
        if (out2) out2[ob + n] = f2bf(fmaxf(v, 0.f));
        if (zeFc) {
          zeFc[((size_t)p << 7) + n] = v;          // compact fp32 (coalesced)
          zeBFc[((size_t)p << 7) + n] = f2bf(v);   // compact bf16 for VQ
        }
      }
    }
  }
}

// ---------------- VQ: scores = ze . cb^T, per-pixel argmin via packed atomicMin ----------------
// BK=128 -> single chunk, single 32KB LDS buffer, one barrier total.
__global__ __launch_bounds__(256, 2) void vq_score(
    const u16* __restrict__ zeBF, const u16* __restrict__ cbF,
    const float* __restrict__ cbn, unsigned long long* __restrict__ minbuf)
{
  __shared__ u16 lA[16384];
  const int tid = threadIdx.x;
  const int w = tid >> 6, lane = tid & 63, quad = lane >> 4, l16 = lane & 15;
  const int wm = w >> 1, wn = w & 1;
  const int bx = ((blockIdx.x & 7) << 6) | (blockIdx.x >> 3);
  const int blockM = bx << 7;
  const int nb = blockIdx.y;
  const int swz3 = (tid & 7) ^ ((tid >> 3) & 7);
  const int wBase = (tid >> 3)*128 + swz3*8;
  const u16* gA[4];
#pragma unroll
  for (int i=0;i<4;i++)
    gA[i] = zeBF + ((size_t)(blockM + i*32 + (tid >> 3)) << 7) + (tid & 7)*8;
  const u16* gBf = cbF + (nb << 14) + (wn*64 + l16)*32 + quad*8;

  floatx4 zz = {0.f,0.f,0.f,0.f};
  floatx4 acc[4][4];
#pragma unroll
  for (int i=0;i<4;i++)
#pragma unroll
    for (int j=0;j<4;j++) acc[i][j] = zz;

  auto loadBk = [&](int kk, short8 (&v)[4]) {
    const u16* p = gBf + kk*4096;
#pragma unroll
    for (int s4=0;s4<4;s4++) v[s4] = *(const short8*)(p + s4*512);
  };
  auto computeH = [&](int kk, short8 (&bfr)[4]) {
    short8 af[4];
#pragma unroll
    for (int s4=0;s4<4;s4++) {
      const int row = wm*64 + s4*16 + l16;
      af[s4] = *(const short8*)&lA[row*128 + (((kk*4 + quad) ^ (l16 & 7)) << 3)];
    }
#pragma unroll
    for (int i=0;i<4;i++)
#pragma unroll
      for (int j=0;j<4;j++)
        acc[i][j] = __builtin_amdgcn_mfma_f32_16x16x32_bf16(af[i], bfr[j], acc[i][j], 0, 0, 0);
  };

  short8 a[8], bA[4], bB[4];
#pragma unroll
  for (int i=0;i<4;i++)
#pragma unroll
    for (int h=0;h<2;h++)
      a[i*2+h] = *(const short8*)(gA[i] + h*64);
  loadBk(0, bA);
#pragma unroll
  for (int i=0;i<4;i++)
#pragma unroll
    for (int h=0;h<2;h++)
      *(short8*)(lA + i*4096 + wBase + h*64) = a[i*2+h];
  lgkmbar();
  loadBk(1, bB);
  computeH(0, bA);
  loadBk(2, bA);
  computeH(1, bB);
  loadBk(3, bB);
  computeH(2, bA);
  computeH(3, bB);

  float cn[4];
#pragma unroll
  for (int j=0;j<4;j++) cn[j] = cbn[nb*128 + wn*64 + j*16 + l16];

#pragma unroll
  for (int i=0;i<4;i++) {
#pragma unroll
    for (int r=0;r<4;r++) {
      const int p = blockM + wm*64 + i*16 + quad*4 + r;
      unsigned long long best = 0xFFFFFFFFFFFFFFFFull;
#pragma unroll
      for (int j=0;j<4;j++) {
        const int n = nb*128 + wn*64 + j*16 + l16;
        float v = cn[j] - acc[i][j][r];       // 0.5||e||^2 - z.e  (same argmin as L2 dist)
        unsigned long long pk = ((unsigned long long)fkey(v) << 32) | (unsigned)n;
        if (pk < best) best = pk;
      }
#pragma unroll
      for (int d=1; d<16; d<<=1) {
        unsigned long long o = __shfl_xor(best, d, 64);
        if (o < best) best = o;
      }
      if (l16 == 0) atomicMin(minbuf + p, best);
    }
  }
}

// ---------------- finalize: ze transpose -> NCHW, zq gather -> NCHW + bf16 NHWC, coalesced ----------------
__global__ __launch_bounds__(256) void finalize(
    const float* __restrict__ zeFc, const unsigned long long* __restrict__ minb,
    const float* __restrict__ cb, float* __restrict__ outZe, float* __restrict__ outZq,
    u16* __restrict__ zqI)
{
  __shared__ float T[64*129];
  __shared__ int ns[64];
  const int tid = threadIdx.x;
  const int P0 = blockIdx.x << 6;                 // 64 pixels, same image & h-row
  const int b = P0 >> 12, hw0 = P0 & 4095;

#pragma unroll
  for (int it=0; it<32; ++it) {                   // coalesced read of ze tile
    int e = it*256 + tid;
    int px = e >> 7, c = e & 127;
    T[px*129 + c] = zeFc[((size_t)P0 << 7) + e];
  }
  if (tid < 64) ns[tid] = (int)(unsigned)(minb[P0 + tid] & 0xFFFFFFFFull);
  __syncthreads();

  float* zeB = outZe + (((size_t)b) << 19) + hw0;
  float* zqB = outZq + (((size_t)b) << 19) + hw0;
  const int h = hw0 >> 6;
  u16* zqIB = zqI + b*IS66 + h*RS66;
#pragma unroll
  for (int it=0; it<32; ++it) {
    const int c = it*4 + (tid >> 6);
    const int px = tid & 63;
    zeB[(c << 12) + px] = T[px*129 + c];
    float v = cb[(ns[px] << 7) + c];
    zqB[(c << 12) + px] = v;
    zqIB[px*128 + c] = f2bf(v);
  }
}

// ---------------- zero halos + init VQ argmin buffer ----------------
__global__ __launch_bounds__(256) void zero_halos(
    u16* big, u16* s0, u16* s1, u16* s2, u16* s3, unsigned long long* minb)
{
  int id = blockIdx.x*256 + threadIdx.x;
  if (id >= 463872) return;
  if (id >= 398336) { minb[id - 398336] = 0xFFFFFFFFFFFFFFFFull; return; }
  u16* base; int H, W;
  if (id < 132096) { base = big; H = 128; W = 128; }
  else {
    id -= 132096;
    int bi = id / 66560;
    id -= bi*66560;
    base = (bi == 0) ? s0 : (bi == 1) ? s1 : (bi == 2) ? s2 : s3;
    H = 64; W = 64;
  }
  int Wp = W+2, Hp = H+2;
  int cv = id & 15; int rest = id >> 4;
  int npx = 2*Wp + 2*H;
  int img = rest / npx; int pix = rest - img*npx;
  int hh, wwp;
  if (pix < Wp) { hh = 0; wwp = pix; }
  else if (pix < 2*Wp) { hh = Hp-1; wwp = pix - Wp; }
  else { int r2 = pix - 2*Wp; hh = 1 + (r2 >> 1); wwp = (r2 & 1) ? (Wp-1) : 0; }
  uint4 zv = {0u,0u,0u,0u};
  *(uint4*)(base + (((size_t)img*Hp + hh)*Wp + wwp)*128 + cv*8) = zv;
}

// ---------------- weight prep ----------------
struct WEnt { const float* src; u16* dst; int O, I, T, mode; };
struct WTab { int n; WEnt e[16]; int cum[17]; };
__global__ __launch_bounds__(256) void prep_w(WTab wt) {
  int id = blockIdx.x*256 + threadIdx.x;
  if (id >= wt.cum[wt.n]) return;
  int k = 0;
  while (id >= wt.cum[k+1]) k++;
  int l = id - wt.cum[k];
  WEnt E = wt.e[k];
  if (E.mode == 6) {                        // frag-major conv weights: [tap][kk4][row][quad][8]
    int e = l & 7, quad = (l >> 3) & 3, row = (l >> 5) & 127;
    int kk = (l >> 12) & 3, t = l >> 14;
    int i = kk*32 + quad*8 + e;
    E.dst[l] = f2bf(E.src[(row*E.I + i)*E.T + t]);
  } else if (E.mode == 1) {                 // convT dt1 frag-major: [cls][tt][kk4][row][quad][8]
    int e = l & 7, quad = (l >> 3) & 3, row = (l >> 5) & 127;
    int kk = (l >> 12) & 3, tt = (l >> 14) & 3, cls = l >> 16;
    int i = kk*32 + quad*8 + e;
    int th = tt >> 1, tw = tt & 1, po = cls >> 1, pw = cls & 1;
    int kh = po ? (th ? 2 : 0) : (th ? 3 : 1);
    int kw = pw ? (tw ? 2 : 0) : (tw ? 3 : 1);
    E.dst[l] = f2bf(E.src[((i*128 + row)*4 + kh)*4 + kw]);
  } else if (E.mode == 7) {                 // frag-major codebook: [tile][kk4][row][quad][8]
    int e = l & 7, quad = (l >> 3) & 3, row = (l >> 5) & 127;
    int kk = (l >> 12) & 3, tt = l >> 14;
    int i = kk*32 + quad*8 + e;
    E.dst[l] = f2bf(E.src[(tt*128 + row)*128 + i]);
  } else if (E.mode == 3) {                 // codebook 0.5*||e||^2
    float s = 0.f; const float* r = E.src + l*128;
    for (int c=0;c<128;c++) s += r[c]*r[c];
    ((float*)E.dst)[l] = 0.5f*s;
  } else if (E.mode == 4) {                 // e1 weights fp32 [o][48] -> [tap][o]
    int o = l & 127, tap = l >> 7;
    ((float*)E.dst)[l] = E.src[o*48 + tap];
  } else {                                  // mode 5: dt2 [c128][o3][4][4] -> bf16 [n48][c128]
    int c = l & 127, n = l >> 7;            // n = o*16 + kh*4+kw
    int o = n >> 4, kk = n & 15;
    E.dst[l] = f2bf(E.src[c*48 + o*16 + kk]);
  }
}

// ---------------- e1: 3->128, k4 s2 p1, row-tiled direct fp32, relu -> bf16 NHWC halo ----------------
__global__ __launch_bounds__(256) void conv_e1(
    const float* __restrict__ x, const float* __restrict__ wT,   // wT: [tap48][o128] fp32
    const float* __restrict__ bias, u16* __restrict__ outI)
{
  __shared__ float inS[12*260];
  __shared__ float wS[48*128];
  __shared__ float bS[128];
  const int tid = threadIdx.x;
  const int b = blockIdx.x >> 7, ho = blockIdx.x & 127;

  for (int l = tid; l < 1536; l += 256)
    ((float4*)wS)[l] = ((const float4*)wT)[l];
  if (tid < 128) bS[tid] = bias[tid];
  for (int l = tid; l < 3120; l += 256) {
    int col = l % 260; int rest = l / 260;
    int kh = rest & 3, c = rest >> 2;
    int hi = 2*ho + kh - 1, wi = col - 1;
    float v = 0.f;
    if ((unsigned)hi < 256u && (unsigned)wi < 256u)
      v = x[((b*3 + c) << 16) + (hi << 8) + wi];
    inS[rest*260 + col] = v;
  }
  __syncthreads();

  const int g = tid & 7;
  const int pxg = tid >> 3;
  floatx4 acc[4][4];
  {
    const floatx4* bp = (const floatx4*)&bS[g*16];
    floatx4 b0 = bp[0], b1 = bp[1], b2 = bp[2], b3 = bp[3];
#pragma unroll
    for (int px=0;px<4;px++) { acc[px][0]=b0; acc[px][1]=b1; acc[px][2]=b2; acc[px][3]=b3; }
  }
#pragma unroll
  for (int c=0;c<3;c++)
#pragma unroll
    for (int kh=0;kh<4;kh++) {
      const float* row = &inS[(c*4+kh)*260];
#pragma unroll
      for (int kw=0;kw<4;kw++) {
        const int tap = c*16 + kh*4 + kw;
        const floatx4* wp = (const floatx4*)&wS[tap*128 + g*16];
        floatx4 w0 = wp[0], w1 = wp[1], w2 = wp[2], w3 = wp[3];
#pragma unroll
        for (int px=0;px<4;px++) {
          float xv = row[((pxg*4 + px) << 1) + kw];
          acc[px][0] += xv*w0; acc[px][1] += xv*w1;
          acc[px][2] += xv*w2; acc[px][3] += xv*w3;
        }
      }
    }

  u16* ob = outI + b*IS130 + ho*RS130;
#pragma unroll
  for (int px=0;px<4;px++) {
    const int wo = pxg*4 + px;
    u16* p = ob + wo*128 + g*16;
#pragma unroll
    for (int k=0;k<4;k++) {
      union { u16 u[4]; uint2 v2; } pk;
#pragma unroll
      for (int j=0;j<4;j++) pk.u[j] = f2bf(fmaxf(acc[px][k][j], 0.f));
      *(uint2*)(p + k*4) = pk.v2;
    }
  }
}

// ---------------- dt2 GEMM: cols[p][48] = in[p][128ch] . Wb[48][128]^T, MFMA, no LDS ----------------
__global__ __launch_bounds__(256) void dt2_gemm(
    const u16* __restrict__ inI, const u16* __restrict__ Wb,
    float* __restrict__ cols)
{
  const int tid = threadIdx.x;
  const int w = tid >> 6, lane = tid & 63, quad = lane >> 4, l16 = lane & 15;
  const int pixBase = blockIdx.x*256 + w*64;

  short8 Bf[3][4];
#pragma unroll
  for (int nt=0; nt<3; nt++)
#pragma unroll
    for (int kc=0; kc<4; kc++)
      Bf[nt][kc] = *(const short8*)(Wb + (nt*16 + l16)*128 + kc*32 + quad*8);

  const u16* ap[4];
#pragma unroll
  for (int ms=0; ms<4; ms++) {
    int p = pixBase + ms*16 + l16;
    int b = p >> 14, rem = p & 16383;
    ap[ms] = inI + b*IS130 + (rem >> 7)*RS130 + (rem & 127)*128;
  }

  floatx4 zz = {0.f,0.f,0.f,0.f};
  floatx4 acc[4][3];
#pragma unroll
  for (int ms=0; ms<4; ms++)
#pragma unroll
    for (int nt=0; nt<3; nt++) acc[ms][nt] = zz;

#pragma unroll
  for (int kc=0; kc<4; kc++) {
#pragma unroll
    for (int ms=0; ms<4; ms++) {
      short8 a = *(const short8*)(ap[ms] + kc*32 + quad*8);
#pragma unroll
      for (int nt=0; nt<3; nt++)
        acc[ms][nt] = __builtin_amdgcn_mfma_f32_16x16x32_bf16(a, Bf[nt][kc], acc[ms][nt], 0, 0, 0);
    }
  }

#pragma unroll
  for (int ms=0; ms<4; ms++)
#pragma unroll
    for (int nt=0; nt<3; nt++)
#pragma unroll
      for (int r=0; r<4; r++) {
        int p = pixBase + ms*16 + quad*4 + r;
        cols[(size_t)p*48 + nt*16 + l16] = acc[ms][nt][r];
      }
}

// ---------------- dt2 gather: col2im + bias -> NCHW fp32 ----------------
__global__ __launch_bounds__(256) void dt2_gather(
    const float* __restrict__ cols, const float* __restrict__ bias,
    float* __restrict__ xhat)
{
  int id = blockIdx.x*256 + threadIdx.x;
  int b = id >> 16, rem = id & 65535;
  int ho = rem >> 8, wo = rem & 255;
  const int ph = ho & 1, pw = wo & 1;
  const int hi0 = ph ? ((ho+1)>>1) : (ho>>1);
  const int kh0 = ph ? 0 : 1;
  const int wi0 = pw ? ((wo+1)>>1) : (wo>>1);
  const int kw0 = pw ? 0 : 1;
  float a0 = bias[0], a1 = bias[1], a2 = bias[2];
#pragma unroll
  for (int th=0; th<2; th++) {
    const int hi = hi0 - th;
    if ((unsigned)hi >= 128u) continue;
    const int kh = kh0 + 2*th;
#pragma unroll
    for (int tw=0; tw<2; tw++) {
      const int wi = wi0 - tw;
      if ((unsigned)wi >= 128u) continue;
      const int kw = kw0 + 2*tw;
      const float* r = cols + (size_t)((b << 14) + (hi << 7) + wi)*48 + (kh*4 + kw);
      a0 += r[0]; a1 += r[16]; a2 += r[32];
    }
  }
  const int ob = ((b*3) << 16) + (ho << 8) + wo;
  xhat[ob]          = a0;
  xhat[ob + 65536]  = a1;
  xhat[ob + 131072] = a2;
}

// =====================================================================================
extern "C" void kernel_launch(void* const* d_in, const int* in_sizes, int n_in,
                              void* d_out, int out_size, void* d_ws, size_t ws_size,
                              hipStream_t stream)
{
  const float* x     = (const float*)d_in[0];
  const float* e1w   = (const float*)d_in[1];
  const float* e1b   = (const float*)d_in[2];
  const float* e2w   = (const float*)d_in[3];
  const float* e2b   = (const float*)d_in[4];
  const float* e3w   = (const float*)d_in[5];
  const float* e3b   = (const float*)d_in[6];
  const float* er1aw = (const float*)d_in[7];
  const float* er1ab = (const float*)d_in[8];
  const float* er1bw = (const float*)d_in[9];
  const float* er1bb = (const float*)d_in[10];
  const float* er2aw = (const float*)d_in[11];
  const float* er2ab = (const float*)d_in[12];
  const float* er2bw = (const float*)d_in[13];
  const float* er2bb = (const float*)d_in[14];
  const float* cb    = (const float*)d_in[15];
  const float* d1w   = (const float*)d_in[16];
  const float* d1b   = (const float*)d_in[17];
  const float* dr1aw = (const float*)d_in[18];
  const float* dr1ab = (const float*)d_in[19];
  const float* dr1bw = (const float*)d_in[20];
  const float* dr1bb = (const float*)d_in[21];
  const float* dr2aw = (const float*)d_in[22];
  const float* dr2ab = (const float*)d_in[23];
  const float* dr2bw = (const float*)d_in[24];
  const float* dr2bb = (const float*)d_in[25];
  const float* dt1w  = (const float*)d_in[26];
  const float* dt1b  = (const float*)d_in[27];
  const float* dt2w  = (const float*)d_in[28];
  const float* dt2b  = (const float*)d_in[29];
  float* out = (float*)d_out;

  char* ws = (char*)d_ws;
  size_t off = 0;
  auto alloc = [&](size_t bytes) -> void* {
    void* r = ws + off; off += (bytes + 255) & ~(size_t)255; return r;
  };

  u16* BIG = (u16*)alloc((size_t)IS130*16*2);      // e1-out / ze-compact / dt1-out
  u16* S[4];
  for (int i=0;i<4;i++) S[i] = (u16*)alloc((size_t)IS66*16*2);
  unsigned long long* minb = (unsigned long long*)alloc((size_t)65536*8);
  u16* W_e2 = (u16*)alloc(262144*2);
  u16* W9[6]; for (int i=0;i<6;i++) W9[i] = (u16*)alloc(147456*2);
  u16* W1[4]; for (int i=0;i<4;i++) W1[i] = (u16*)alloc(16384*2);
  u16* Wdt1 = (u16*)alloc(262144*2);
  u16* cbBF = (u16*)alloc(65536*2);
  float* cbn = (float*)alloc(512*4);
  float* wsE1 = (float*)alloc(6144*4);
  u16* Wb48 = (u16*)alloc(6144*2);

  u16* BIGi = BIG + RS130 + 128;
  u16* Si[4];
  for (int i=0;i<4;i++) Si[i] = S[i] + RS66 + 128;
  u16* zeBFc = S[1];            // compact bf16 ze (VQ A-matrix), S1 dead by er2b
  float* zeFc = (float*)BIG;    // compact fp32 ze (32MB) — BIG free between e2 and dt1
  float* cols = (float*)S[1];   // dt2 cols fp32 spans S1..S3 (dead by dt2 time)

  // 1. zero halos + init minb
  zero_halos<<<1812, 256, 0, stream>>>(BIG, S[0], S[1], S[2], S[3], minb);

  // 2. weights
  WTab wtab; int ne = 0; wtab.cum[0] = 0;
  auto addw = [&](const float* s, u16* d, int O, int I, int T, int m, int items) {
    wtab.e[ne] = {s, d, O, I, T, m};
    wtab.cum[ne+1] = wtab.cum[ne] + items; ne++;
  };
  addw(e2w,   W_e2, 128,128,16,6, 262144);
  addw(e3w,   W9[0],128,128, 9,6, 147456);
  addw(er1aw, W9[1],128,128, 9,6, 147456);
  addw(er2aw, W9[2],128,128, 9,6, 147456);
  addw(d1w,   W9[3],128,128, 9,6, 147456);
  addw(dr1aw, W9[4],128,128, 9,6, 147456);
  addw(dr2aw, W9[5],128,128, 9,6, 147456);
  addw(er1bw, W1[0],128,128, 1,6, 16384);
  addw(er2bw, W1[1],128,128, 1,6, 16384);
  addw(dr1bw, W1[2],128,128, 1,6, 16384);
  addw(dr2bw, W1[3],128,128, 1,6, 16384);
  addw(dt1w,  Wdt1, 0,0,0,1, 262144);
  addw(cb,    cbBF, 0,0,0,7, 65536);
  addw(cb,    (u16*)cbn, 0,0,0,3, 512);
  addw(e1w,   (u16*)wsE1, 0,0,0,4, 6144);
  addw(dt2w,  Wb48, 0,0,0,5, 6144);
  wtab.n = ne;
  prep_w<<<(wtab.cum[ne] + 255)/256, 256, 0, stream>>>(wtab);

  // 3. e1
  conv_e1<<<2048, 256, 0, stream>>>(x, wsE1, e1b, BIGi);

  // taps
  Taps t16; t16.n = 16; t16.dh2 = 0; t16.dw2 = 0;
  for (int t=0;t<16;t++) { t16.dh2 |= (unsigned)(t>>2) << (2*t); t16.dw2 |= (unsigned)(t&3) << (2*t); }
  Taps t9; t9.n = 9; t9.dh2 = 0; t9.dw2 = 0;
  for (int t=0;t<9;t++) { t9.dh2 |= (unsigned)(t/3) << (2*t); t9.dw2 |= (unsigned)(t%3) << (2*t); }
  Taps t1x; t1x.n = 1; t1x.dh2 = 1; t1x.dw2 = 1;
  Taps tcm; tcm.n = 4; tcm.dh2 = 0; tcm.dw2 = 0;   // packed: 8 bits per class
  for (int cls=0; cls<4; ++cls) {
    int po = cls >> 1, pw = cls & 1;
    for (int tt=0; tt<4; ++tt) {
      int th = tt >> 1, tw = tt & 1;
      int dh = po ? (th ? 0 : 1) : (th ? -1 : 0);
      int dw = pw ? (tw ? 0 : 1) : (tw ? -1 : 0);
      tcm.dh2 |= (unsigned)(dh+1) << (8*cls + 2*tt);
      tcm.dw2 |= (unsigned)(dw+1) << (8*cls + 2*tt);
    }
  }

  auto conv = [&](const u16* in_, int iRS, int iIS, int si,
                  const u16* w_, const float* b_, Taps tp,
                  u16* o_, int oRS, int oIS, int so, int oh, int ow,
                  const u16* r_, u16* o2, int rl, float* zf, u16* zb) {
    conv_mfma<<<512, 256, 0, stream>>>(in_, iRS, iIS, si, w_, b_, tp,
                                       o_, oRS, oIS, so, oh, ow, r_, o2, rl, zf, zb, 0);
  };

  // encoder
  conv(BIGi, RS130, IS130, 2, W_e2, e2b, t16, Si[0], RS66, IS66, 1,0,0, nullptr, nullptr, 1, nullptr, nullptr); // e2 -> S0 (relu)
  conv(Si[0], RS66, IS66, 1, W9[0], e3b, t9, Si[1], RS66, IS66, 1,0,0, nullptr, Si[2], 0, nullptr, nullptr);    // e3 -> t2=S1, relu->S2
  conv(Si[2], RS66, IS66, 1, W9[1], er1ab, t9, Si[0], RS66, IS66, 1,0,0, nullptr, nullptr, 1, nullptr, nullptr);// er1a -> S0 (relu)
  conv(Si[0], RS66, IS66, 1, W1[0], er1bb, t1x, Si[3], RS66, IS66, 1,0,0, Si[1], Si[2], 0, nullptr, nullptr);   // er1b(+t2) -> t4=S3, relu->S2
  conv(Si[2], RS66, IS66, 1, W9[2], er2ab, t9, Si[0], RS66, IS66, 1,0,0, nullptr, nullptr, 1, nullptr, nullptr);// er2a -> S0 (relu)
  conv(Si[0], RS66, IS66, 1, W1[1], er2bb, t1x, nullptr, RS66, IS66, 1,0,0, Si[3], nullptr, 0, zeFc, zeBFc);    // er2b(+t4) -> ze compact (fp32+bf16)

  // VQ + outputs
  vq_score<<<dim3(512,4), 256, 0, stream>>>(zeBFc, cbBF, cbn, minb);
  finalize<<<1024, 256, 0, stream>>>(zeFc, minb, cb, out + 3145728, out + 11534336, Si[2]);  // zq bf16 -> S2

  // decoder
  conv(Si[2], RS66, IS66, 1, W9[3], d1b, t9, Si[0], RS66, IS66, 1,0,0, nullptr, Si[1], 0, nullptr, nullptr);    // d1 -> g1=S0, relu->S1
  conv(Si[1], RS66, IS66, 1, W9[4], dr1ab, t9, Si[2], RS66, IS66, 1,0,0, nullptr, nullptr, 1, nullptr, nullptr);// dr1a -> S2 (relu)
  conv(Si[2], RS66, IS66, 1, W1[2], dr1bb, t1x, Si[3], RS66, IS66, 1,0,0, Si[0], Si[1], 0, nullptr, nullptr);   // dr1b(+g1) -> g2=S3, relu->S1
  conv(Si[1], RS66, IS66, 1, W9[5], dr2ab, t9, Si[2], RS66, IS66, 1,0,0, nullptr, nullptr, 1, nullptr, nullptr);// dr2a -> S2 (relu)
  conv(Si[2], RS66, IS66, 1, W1[3], dr2bb, t1x, Si[0], RS66, IS66, 1,0,0, Si[3], nullptr, 0, nullptr, nullptr); // dr2b(+g2) -> g3=S0

  // dt1: 4 parity classes in one dispatch (blockIdx.y = cls)
  conv_mfma<<<dim3(512,4), 256, 0, stream>>>(Si[0], RS66, IS66, 1, Wdt1, dt1b, tcm,
                                             BIGi, RS130, IS130, 2, 0, 0,
                                             nullptr, nullptr, 1, nullptr, nullptr, 1);

  // dt2: cols GEMM (MFMA) + col2im gather
  dt2_gemm<<<1024, 256, 0, stream>>>(BIGi, Wb48, cols);
  dt2_gather<<<4096, 256, 0, stream>>>(cols, dt2b, out);
}

// Round 7
// 701.648 us; speedup vs baseline: 1.1691x; 1.1157x over previous
//
#include <hip/hip_runtime.h>
#include <stdint.h>

typedef unsigned short u16;
typedef __attribute__((ext_vector_type(8))) short short8;
typedef __attribute__((ext_vector_type(4))) float floatx4;

#define RS66  (66*128)
#define IS66  (66*66*128)
#define RS130 (130*128)
#define IS130 (130*130*128)

__device__ __forceinline__ float bf2f(u16 h) {
  union { unsigned u; float f; } v; v.u = ((unsigned)h) << 16; return v.f;
}
__device__ __forceinline__ u16 f2bf(float f) {
  union { float f; unsigned u; } v; v.f = f;
  unsigned r = v.u + 0x7FFFu + ((v.u >> 16) & 1u);
  return (u16)(r >> 16);
}
__device__ __forceinline__ void gl_lds16(const void* g, void* l) {
  __builtin_amdgcn_global_load_lds(
      (const __attribute__((address_space(1))) void*)(uintptr_t)g,
      (__attribute__((address_space(3))) void*)(uintptr_t)l, 16, 0, 0);
}
__device__ __forceinline__ unsigned fkey(float f) {
  unsigned u = __float_as_uint(f);
  return (u & 0x80000000u) ? ~u : (u | 0x80000000u);
}

struct Taps { int n; unsigned dh2; unsigned dw2; };  // 2-bit packed (d+1); multi: 8 bits/class

// ---------------- MFMA implicit-GEMM conv: tile 128 px x 128 outch, K=taps*128 ----------------
// Round-0 verified structure (gl_lds staging for BOTH A and B, XOR-swizzled global source +
// linear LDS dest + swizzled b128 reads, 0 bank conflicts) with ONE change: the per-chunk
// barrier no longer drains vmcnt to 0 (T4, m218). K-loop vmem is gl_lds-ONLY, so a counted
// FIFO is sound (unlike R2's mixed-type attempt):
//   prologue: A(0),B(0),A(1) issued (12 ops in flight)
//   iter ci:  s_waitcnt vmcnt(4) lgkmcnt(0); s_barrier   // ci's 8 landed; A(ci+1) flying
//             issueB(ci+1) -> lB[(ci+1)&1]               // after barrier: prior readers drained
//             issueA(ci+2) -> lA[(ci+2)%3]               // 3-deep: last read 2 barriers ago
//             compute chunk ci from lA[ci%3], lB[ci&1]
// Loads get 1-2 full chunks of cover and never drain in the main loop. Stray epilogue loads
// hoisted into the loop only make vmcnt(4) more conservative (still correct).
// LDS 48+32=80KB -> 2 blocks/CU; ~90 VGPR (no reg staging).
__global__ __launch_bounds__(256, 2) void conv_mfma(
    const u16* __restrict__ in, int inRS, int inIS, int si,
    const u16* __restrict__ wt, const float* __restrict__ bias, Taps tp,
    u16* __restrict__ out, int outRS, int outIS, int so, int oh0, int ow0,
    const u16* __restrict__ res, u16* __restrict__ out2, int reluMain,
    float* __restrict__ zeFc, u16* __restrict__ zeBFc, int multi)
{
  __shared__ u16 lA[3][8192];
  __shared__ u16 lB[2][8192];
  const int tid = threadIdx.x;
  const int w = tid >> 6, lane = tid & 63, quad = lane >> 4, l16 = lane & 15;
  const int wm = w >> 1, wn = w & 1;
  // XCD swizzle: gridDim.x == 512 always (512 % 8 == 0 -> bijective)
  const int bx = ((blockIdx.x & 7) << 6) | (blockIdx.x >> 3);
  const int blockM = bx << 7;

  unsigned dh2 = tp.dh2, dw2 = tp.dw2;
  if (multi) {
    const int cls = blockIdx.y;
    dh2 = (tp.dh2 >> (8*cls)) & 0xffu;
    dw2 = (tp.dw2 >> (8*cls)) & 0xffu;
    wt += cls << 16;
    oh0 = cls >> 1; ow0 = cls & 1;
  }

  // staging thread mapping: px = i*32 + (tid>>3); 16B chunk cb_global = (tid&7) ^ ((tid>>3)&7)
  const int swz = (tid & 7) ^ ((tid >> 3) & 7);
  const u16* gA[4]; const u16* gB[4];
#pragma unroll
  for (int i=0;i<4;i++) {
    const int pg = blockM + i*32 + (tid >> 3);
    const int b = pg >> 12, mo = (pg >> 6) & 63, no = pg & 63;
    gA[i] = in + b*inIS + si*mo*inRS + si*no*128 + swz*8;
    gB[i] = wt + (i*32 + (tid >> 3))*128 + swz*8;
  }
  // per (issue, wave) LDS base: (i*32 + w*8) rows of 64 u16
  const int ldsOff = w*512;   // u16 units

  floatx4 zz = {0.f,0.f,0.f,0.f};
  floatx4 acc[4][4];
#pragma unroll
  for (int i=0;i<4;i++)
#pragma unroll
    for (int j=0;j<4;j++) acc[i][j] = zz;

  auto issueA = [&](int ci, int buf) {
    const int t = ci >> 1, kc = ci & 1;
    const int dh = (int)((dh2 >> (2*t)) & 3u) - 1;
    const int dw = (int)((dw2 >> (2*t)) & 3u) - 1;
    const int aoff = dh*inRS + dw*128 + kc*64;
#pragma unroll
    for (int i=0;i<4;i++)
      gl_lds16(gA[i] + aoff, &lA[buf][i*2048 + ldsOff]);
  };
  auto issueB = [&](int ci, int buf) {
    const int t = ci >> 1, kc = ci & 1;
    const int boff = (t << 14) + kc*64;
#pragma unroll
    for (int i=0;i<4;i++)
      gl_lds16(gB[i] + boff, &lB[buf][i*2048 + ldsOff]);
  };
  auto computeC = [&](const u16* bufA, const u16* bufB) {
#pragma unroll
    for (int kk=0; kk<2; ++kk) {
      short8 af[4], bfr[4];
#pragma unroll
      for (int s=0;s<4;s++) {
        const int row = wm*64 + s*16 + l16;
        af[s]  = *(const short8*)&bufA[row*64 + (((kk*4 + quad) ^ (l16 & 7)) << 3)];
      }
#pragma unroll
      for (int s=0;s<4;s++) {
        const int row = wn*64 + s*16 + l16;
        bfr[s] = *(const short8*)&bufB[row*64 + (((kk*4 + quad) ^ (l16 & 7)) << 3)];
      }
#pragma unroll
      for (int i=0;i<4;i++)
#pragma unroll
        for (int j=0;j<4;j++)
          acc[i][j] = __builtin_amdgcn_mfma_f32_16x16x32_bf16(af[i], bfr[j], acc[i][j], 0, 0, 0);
    }
  };

  const int NCH = tp.n << 1;             // chunks of K=64 (always even, >= 2)
  issueA(0, 0);
  issueB(0, 0);
  issueA(1, 1);
  int ab = 0;                            // ci % 3
  for (int ci = 0; ci < NCH; ++ci) {
    if (ci + 1 < NCH) {
      asm volatile("s_waitcnt vmcnt(4) lgkmcnt(0)" ::: "memory");  // ci landed; A(ci+1) in flight
    } else {
      asm volatile("s_waitcnt vmcnt(0) lgkmcnt(0)" ::: "memory");  // final drain
    }
    __builtin_amdgcn_s_barrier();
    __builtin_amdgcn_sched_barrier(0);
    if (ci + 1 < NCH) issueB(ci + 1, (ci + 1) & 1);
    int a2 = ab + 2; if (a2 >= 3) a2 -= 3;
    if (ci + 2 < NCH) issueA(ci + 2, a2);
    computeC(&lA[ab][0], &lB[ci & 1][0]);
    ab = (ab + 1 == 3) ? 0 : ab + 1;
  }

  float bv[4];
#pragma unroll
  for (int j=0;j<4;j++) bv[j] = bias[wn*64 + j*16 + l16];

#pragma unroll
  for (int i=0;i<4;i++) {
#pragma unroll
    for (int r=0;r<4;r++) {
      const int p = blockM + wm*64 + i*16 + quad*4 + r;
      const int bb = p >> 12, mo = (p >> 6) & 63, no = p & 63;
      const int ob = bb*outIS + (so*mo + oh0)*outRS + (so*no + ow0)*128;
#pragma unroll
      for (int j=0;j<4;j++) {
        const int n = wn*64 + j*16 + l16;
        float v = acc[i][j][r] + bv[j];
        if (res)  v += bf2f(res[ob + n]);
        if (out)  out[ob + n]  = f2bf(reluMain ? fmaxf(v, 0.f) : v);
        if (out2) out2[ob + n] = f2bf(fmaxf(v, 0.f));
        if (zeFc) {
          zeFc[((size_t)p << 7) + n] = v;          // compact fp32 (coalesced)
          zeBFc[((size_t)p << 7) + n] = f2bf(v);   // compact bf16 for VQ
        }
      }
    }
  }
}

// ---------------- VQ: scores = ze . cb^T, per-pixel argmin via packed atomicMin ----------------
__global__ __launch_bounds__(256) void vq_score(
    const u16* __restrict__ zeBF, const u16* __restrict__ cbBF,
    const float* __restrict__ cbn, unsigned long long* __restrict__ minbuf)
{
  __shared__ u16 lA[4096];
  __shared__ u16 lB[4096];
  const int tid = threadIdx.x;
  const int w = tid >> 6, lane = tid & 63, quad = lane >> 4, l16 = lane & 15;
  const int wm = w >> 1, wn = w & 1;
  const int q = tid & 3, p0 = tid >> 2;
  const int blockM = blockIdx.x << 7;
  const int nb = blockIdx.y;
  const u16* gA0 = zeBF + ((blockM + p0) << 7) + q*8;
  const u16* gA1 = gA0 + (64 << 7);
  const u16* gB0 = cbBF + ((nb*128 + p0) << 7) + q*8;
  const u16* gB1 = gB0 + (64 << 7);
  u16* lsA0 = lA + w*512; u16* lsA1 = lsA0 + 2048;
  u16* lsB0 = lB + w*512; u16* lsB1 = lsB0 + 2048;

  floatx4 zz = {0.f,0.f,0.f,0.f};
  floatx4 acc[4][4];
#pragma unroll
  for (int i=0;i<4;i++)
#pragma unroll
    for (int j=0;j<4;j++) acc[i][j] = zz;

#pragma unroll
  for (int kc = 0; kc < 4; ++kc) {
    __syncthreads();
    gl_lds16(gA0 + kc*32, lsA0);
    gl_lds16(gA1 + kc*32, lsA1);
    gl_lds16(gB0 + kc*32, lsB0);
    gl_lds16(gB1 + kc*32, lsB1);
    __syncthreads();
    short8 af[4], bfr[4];
#pragma unroll
    for (int s=0;s<4;s++) af[s]  = *(const short8*)&lA[(wm*64 + s*16 + l16)*32 + quad*8];
#pragma unroll
    for (int s=0;s<4;s++) bfr[s] = *(const short8*)&lB[(wn*64 + s*16 + l16)*32 + quad*8];
#pragma unroll
    for (int i=0;i<4;i++)
#pragma unroll
      for (int j=0;j<4;j++)
        acc[i][j] = __builtin_amdgcn_mfma_f32_16x16x32_bf16(af[i], bfr[j], acc[i][j], 0, 0, 0);
  }

  float cn[4];
#pragma unroll
  for (int j=0;j<4;j++) cn[j] = cbn[nb*128 + wn*64 + j*16 + l16];

#pragma unroll
  for (int i=0;i<4;i++) {
#pragma unroll
    for (int r=0;r<4;r++) {
      const int p = blockM + wm*64 + i*16 + quad*4 + r;
      unsigned long long best = 0xFFFFFFFFFFFFFFFFull;
#pragma unroll
      for (int j=0;j<4;j++) {
        const int n = nb*128 + wn*64 + j*16 + l16;
        float v = cn[j] - acc[i][j][r];       // 0.5||e||^2 - z.e  (same argmin as L2 dist)
        unsigned long long pk = ((unsigned long long)fkey(v) << 32) | (unsigned)n;
        if (pk < best) best = pk;
      }
#pragma unroll
      for (int d=1; d<16; d<<=1) {
        unsigned long long o = __shfl_xor(best, d, 64);
        if (o < best) best = o;
      }
      if (l16 == 0) atomicMin(minbuf + p, best);
    }
  }
}

// ---------------- finalize: ze transpose -> NCHW, zq gather -> NCHW + bf16 NHWC, coalesced ----------------
__global__ __launch_bounds__(256) void finalize(
    const float* __restrict__ zeFc, const unsigned long long* __restrict__ minb,
    const float* __restrict__ cb, float* __restrict__ outZe, float* __restrict__ outZq,
    u16* __restrict__ zqI)
{
  __shared__ float T[64*129];
  __shared__ int ns[64];
  const int tid = threadIdx.x;
  const int P0 = blockIdx.x << 6;                 // 64 pixels, same image & h-row
  const int b = P0 >> 12, hw0 = P0 & 4095;

#pragma unroll
  for (int it=0; it<32; ++it) {                   // coalesced read of ze tile
    int e = it*256 + tid;
    int px = e >> 7, c = e & 127;
    T[px*129 + c] = zeFc[((size_t)P0 << 7) + e];
  }
  if (tid < 64) ns[tid] = (int)(unsigned)(minb[P0 + tid] & 0xFFFFFFFFull);
  __syncthreads();

  float* zeB = outZe + (((size_t)b) << 19) + hw0;
  float* zqB = outZq + (((size_t)b) << 19) + hw0;
  const int h = hw0 >> 6;
  u16* zqIB = zqI + b*IS66 + h*RS66;
#pragma unroll
  for (int it=0; it<32; ++it) {
    const int c = it*4 + (tid >> 6);
    const int px = tid & 63;
    zeB[(c << 12) + px] = T[px*129 + c];
    float v = cb[(ns[px] << 7) + c];
    zqB[(c << 12) + px] = v;
    zqIB[px*128 + c] = f2bf(v);
  }
}

// ---------------- zero halos + init VQ argmin buffer ----------------
__global__ __launch_bounds__(256) void zero_halos(
    u16* big, u16* s0, u16* s1, u16* s2, u16* s3, unsigned long long* minb)
{
  int id = blockIdx.x*256 + threadIdx.x;
  if (id >= 463872) return;
  if (id >= 398336) { minb[id - 398336] = 0xFFFFFFFFFFFFFFFFull; return; }
  u16* base; int H, W;
  if (id < 132096) { base = big; H = 128; W = 128; }
  else {
    id -= 132096;
    int bi = id / 66560;
    id -= bi*66560;
    base = (bi == 0) ? s0 : (bi == 1) ? s1 : (bi == 2) ? s2 : s3;
    H = 64; W = 64;
  }
  int Wp = W+2, Hp = H+2;
  int cv = id & 15; int rest = id >> 4;
  int npx = 2*Wp + 2*H;
  int img = rest / npx; int pix = rest - img*npx;
  int hh, wwp;
  if (pix < Wp) { hh = 0; wwp = pix; }
  else if (pix < 2*Wp) { hh = Hp-1; wwp = pix - Wp; }
  else { int r2 = pix - 2*Wp; hh = 1 + (r2 >> 1); wwp = (r2 & 1) ? (Wp-1) : 0; }
  uint4 zv = {0u,0u,0u,0u};
  *(uint4*)(base + (((size_t)img*Hp + hh)*Wp + wwp)*128 + cv*8) = zv;
}

// ---------------- weight prep ----------------
struct WEnt { const float* src; u16* dst; int O, I, T, mode; };
struct WTab { int n; WEnt e[16]; int cum[17]; };
__global__ __launch_bounds__(256) void prep_w(WTab wt) {
  int id = blockIdx.x*256 + threadIdx.x;
  if (id >= wt.cum[wt.n]) return;
  int k = 0;
  while (id >= wt.cum[k+1]) k++;
  int l = id - wt.cum[k];
  WEnt E = wt.e[k];
  if (E.mode == 0) {
    int i = l % E.I; int rest = l / E.I; int o = rest % E.O; int t = rest / E.O;
    E.dst[l] = f2bf(E.src[(o*E.I + i)*E.T + t]);
  } else if (E.mode == 1) {                 // convT dt1: [I][O][4][4] -> [cls][tt][O][I]
    int i = l & 127, o = (l >> 7) & 127, tt = (l >> 14) & 3, cls = l >> 16;
    int th = tt >> 1, tw = tt & 1, po = cls >> 1, pw = cls & 1;
    int kh = po ? (th ? 2 : 0) : (th ? 3 : 1);
    int kw = pw ? (tw ? 2 : 0) : (tw ? 3 : 1);
    E.dst[l] = f2bf(E.src[((i*128 + o)*4 + kh)*4 + kw]);
  } else if (E.mode == 2) {                 // codebook cast
    E.dst[l] = f2bf(E.src[l]);
  } else if (E.mode == 3) {                 // codebook 0.5*||e||^2
    float s = 0.f; const float* r = E.src + l*128;
    for (int c=0;c<128;c++) s += r[c]*r[c];
    ((float*)E.dst)[l] = 0.5f*s;
  } else if (E.mode == 4) {                 // e1 weights fp32 [o][48] -> [tap][o]
    int o = l & 127, tap = l >> 7;
    ((float*)E.dst)[l] = E.src[o*48 + tap];
  } else {                                  // mode 5: dt2 [c128][o3][4][4] -> bf16 [n48][c128]
    int c = l & 127, n = l >> 7;            // n = o*16 + kh*4+kw
    int o = n >> 4, kk = n & 15;
    E.dst[l] = f2bf(E.src[c*48 + o*16 + kk]);
  }
}

// ---------------- e1: 3->128, k4 s2 p1, row-tiled direct fp32, relu -> bf16 NHWC halo ----------------
__global__ __launch_bounds__(256) void conv_e1(
    const float* __restrict__ x, const float* __restrict__ wT,   // wT: [tap48][o128] fp32
    const float* __restrict__ bias, u16* __restrict__ outI)
{
  __shared__ float inS[12*260];
  __shared__ float wS[48*128];
  __shared__ float bS[128];
  const int tid = threadIdx.x;
  const int b = blockIdx.x >> 7, ho = blockIdx.x & 127;

  for (int l = tid; l < 1536; l += 256)
    ((float4*)wS)[l] = ((const float4*)wT)[l];
  if (tid < 128) bS[tid] = bias[tid];
  for (int l = tid; l < 3120; l += 256) {
    int col = l % 260; int rest = l / 260;
    int kh = rest & 3, c = rest >> 2;
    int hi = 2*ho + kh - 1, wi = col - 1;
    float v = 0.f;
    if ((unsigned)hi < 256u && (unsigned)wi < 256u)
      v = x[((b*3 + c) << 16) + (hi << 8) + wi];
    inS[rest*260 + col] = v;
  }
  __syncthreads();

  const int g = tid & 7;
  const int pxg = tid >> 3;
  floatx4 acc[4][4];
  {
    const floatx4* bp = (const floatx4*)&bS[g*16];
    floatx4 b0 = bp[0], b1 = bp[1], b2 = bp[2], b3 = bp[3];
#pragma unroll
    for (int px=0;px<4;px++) { acc[px][0]=b0; acc[px][1]=b1; acc[px][2]=b2; acc[px][3]=b3; }
  }
#pragma unroll
  for (int c=0;c<3;c++)
#pragma unroll
    for (int kh=0;kh<4;kh++) {
      const float* row = &inS[(c*4+kh)*260];
#pragma unroll
      for (int kw=0;kw<4;kw++) {
        const int tap = c*16 + kh*4 + kw;
        const floatx4* wp = (const floatx4*)&wS[tap*128 + g*16];
        floatx4 w0 = wp[0], w1 = wp[1], w2 = wp[2], w3 = wp[3];
#pragma unroll
        for (int px=0;px<4;px++) {
          float xv = row[((pxg*4 + px) << 1) + kw];
          acc[px][0] += xv*w0; acc[px][1] += xv*w1;
          acc[px][2] += xv*w2; acc[px][3] += xv*w3;
        }
      }
    }

  u16* ob = outI + b*IS130 + ho*RS130;
#pragma unroll
  for (int px=0;px<4;px++) {
    const int wo = pxg*4 + px;
    u16* p = ob + wo*128 + g*16;
#pragma unroll
    for (int k=0;k<4;k++) {
      union { u16 u[4]; uint2 v2; } pk;
#pragma unroll
      for (int j=0;j<4;j++) pk.u[j] = f2bf(fmaxf(acc[px][k][j], 0.f));
      *(uint2*)(p + k*4) = pk.v2;
    }
  }
}

// ---------------- dt2 GEMM: cols[p][48] = in[p][128ch] . Wb[48][128]^T, MFMA, no LDS ----------------
__global__ __launch_bounds__(256) void dt2_gemm(
    const u16* __restrict__ inI, const u16* __restrict__ Wb,
    float* __restrict__ cols)
{
  const int tid = threadIdx.x;
  const int w = tid >> 6, lane = tid & 63, quad = lane >> 4, l16 = lane & 15;
  const int pixBase = blockIdx.x*256 + w*64;

  short8 Bf[3][4];
#pragma unroll
  for (int nt=0; nt<3; nt++)
#pragma unroll
    for (int kc=0; kc<4; kc++)
      Bf[nt][kc] = *(const short8*)(Wb + (nt*16 + l16)*128 + kc*32 + quad*8);

  const u16* ap[4];
#pragma unroll
  for (int ms=0; ms<4; ms++) {
    int p = pixBase + ms*16 + l16;
    int b = p >> 14, rem = p & 16383;
    ap[ms] = inI + b*IS130 + (rem >> 7)*RS130 + (rem & 127)*128;
  }

  floatx4 zz = {0.f,0.f,0.f,0.f};
  floatx4 acc[4][3];
#pragma unroll
  for (int ms=0; ms<4; ms++)
#pragma unroll
    for (int nt=0; nt<3; nt++) acc[ms][nt] = zz;

#pragma unroll
  for (int kc=0; kc<4; kc++) {
#pragma unroll
    for (int ms=0; ms<4; ms++) {
      short8 a = *(const short8*)(ap[ms] + kc*32 + quad*8);
#pragma unroll
      for (int nt=0; nt<3; nt++)
        acc[ms][nt] = __builtin_amdgcn_mfma_f32_16x16x32_bf16(a, Bf[nt][kc], acc[ms][nt], 0, 0, 0);
    }
  }

#pragma unroll
  for (int ms=0; ms<4; ms++)
#pragma unroll
    for (int nt=0; nt<3; nt++)
#pragma unroll
      for (int r=0; r<4; r++) {
        int p = pixBase + ms*16 + quad*4 + r;
        cols[(size_t)p*48 + nt*16 + l16] = acc[ms][nt][r];
      }
}

// ---------------- dt2 gather: col2im + bias -> NCHW fp32 ----------------
__global__ __launch_bounds__(256) void dt2_gather(
    const float* __restrict__ cols, const float* __restrict__ bias,
    float* __restrict__ xhat)
{
  int id = blockIdx.x*256 + threadIdx.x;
  int b = id >> 16, rem = id & 65535;
  int ho = rem >> 8, wo = rem & 255;
  const int ph = ho & 1, pw = wo & 1;
  const int hi0 = ph ? ((ho+1)>>1) : (ho>>1);
  const int kh0 = ph ? 0 : 1;
  const int wi0 = pw ? ((wo+1)>>1) : (wo>>1);
  const int kw0 = pw ? 0 : 1;
  float a0 = bias[0], a1 = bias[1], a2 = bias[2];
#pragma unroll
  for (int th=0; th<2; th++) {
    const int hi = hi0 - th;
    if ((unsigned)hi >= 128u) continue;
    const int kh = kh0 + 2*th;
#pragma unroll
    for (int tw=0; tw<2; tw++) {
      const int wi = wi0 - tw;
      if ((unsigned)wi >= 128u) continue;
      const int kw = kw0 + 2*tw;
      const float* r = cols + (size_t)((b << 14) + (hi << 7) + wi)*48 + (kh*4 + kw);
      a0 += r[0]; a1 += r[16]; a2 += r[32];
    }
  }
  const int ob = ((b*3) << 16) + (ho << 8) + wo;
  xhat[ob]          = a0;
  xhat[ob + 65536]  = a1;
  xhat[ob + 131072] = a2;
}

// =====================================================================================
extern "C" void kernel_launch(void* const* d_in, const int* in_sizes, int n_in,
                              void* d_out, int out_size, void* d_ws, size_t ws_size,
                              hipStream_t stream)
{
  const float* x     = (const float*)d_in[0];
  const float* e1w   = (const float*)d_in[1];
  const float* e1b   = (const float*)d_in[2];
  const float* e2w   = (const float*)d_in[3];
  const float* e2b   = (const float*)d_in[4];
  const float* e3w   = (const float*)d_in[5];
  const float* e3b   = (const float*)d_in[6];
  const float* er1aw = (const float*)d_in[7];
  const float* er1ab = (const float*)d_in[8];
  const float* er1bw = (const float*)d_in[9];
  const float* er1bb = (const float*)d_in[10];
  const float* er2aw = (const float*)d_in[11];
  const float* er2ab = (const float*)d_in[12];
  const float* er2bw = (const float*)d_in[13];
  const float* er2bb = (const float*)d_in[14];
  const float* cb    = (const float*)d_in[15];
  const float* d1w   = (const float*)d_in[16];
  const float* d1b   = (const float*)d_in[17];
  const float* dr1aw = (const float*)d_in[18];
  const float* dr1ab = (const float*)d_in[19];
  const float* dr1bw = (const float*)d_in[20];
  const float* dr1bb = (const float*)d_in[21];
  const float* dr2aw = (const float*)d_in[22];
  const float* dr2ab = (const float*)d_in[23];
  const float* dr2bw = (const float*)d_in[24];
  const float* dr2bb = (const float*)d_in[25];
  const float* dt1w  = (const float*)d_in[26];
  const float* dt1b  = (const float*)d_in[27];
  const float* dt2w  = (const float*)d_in[28];
  const float* dt2b  = (const float*)d_in[29];
  float* out = (float*)d_out;

  char* ws = (char*)d_ws;
  size_t off = 0;
  auto alloc = [&](size_t bytes) -> void* {
    void* r = ws + off; off += (bytes + 255) & ~(size_t)255; return r;
  };

  u16* BIG = (u16*)alloc((size_t)IS130*16*2);      // e1-out / ze-compact / dt1-out
  u16* S[4];
  for (int i=0;i<4;i++) S[i] = (u16*)alloc((size_t)IS66*16*2);
  unsigned long long* minb = (unsigned long long*)alloc((size_t)65536*8);
  u16* W_e2 = (u16*)alloc(262144*2);
  u16* W9[6]; for (int i=0;i<6;i++) W9[i] = (u16*)alloc(147456*2);
  u16* W1[4]; for (int i=0;i<4;i++) W1[i] = (u16*)alloc(16384*2);
  u16* Wdt1 = (u16*)alloc(262144*2);
  u16* cbBF = (u16*)alloc(65536*2);
  float* cbn = (float*)alloc(512*4);
  float* wsE1 = (float*)alloc(6144*4);
  u16* Wb48 = (u16*)alloc(6144*2);

  u16* BIGi = BIG + RS130 + 128;
  u16* Si[4];
  for (int i=0;i<4;i++) Si[i] = S[i] + RS66 + 128;
  u16* zeBFc = S[1];            // compact bf16 ze (VQ A-matrix), S1 dead by er2b
  float* zeFc = (float*)BIG;    // compact fp32 ze (32MB) — BIG free between e2 and dt1
  float* cols = (float*)S[1];   // dt2 cols fp32 spans S1..S3 (dead by dt2 time)

  // 1. zero halos + init minb
  zero_halos<<<1812, 256, 0, stream>>>(BIG, S[0], S[1], S[2], S[3], minb);

  // 2. weights
  WTab wtab; int ne = 0; wtab.cum[0] = 0;
  auto addw = [&](const float* s, u16* d, int O, int I, int T, int m, int items) {
    wtab.e[ne] = {s, d, O, I, T, m};
    wtab.cum[ne+1] = wtab.cum[ne] + items; ne++;
  };
  addw(e2w,   W_e2, 128,128,16,0, 262144);
  addw(e3w,   W9[0],128,128, 9,0, 147456);
  addw(er1aw, W9[1],128,128, 9,0, 147456);
  addw(er2aw, W9[2],128,128, 9,0, 147456);
  addw(d1w,   W9[3],128,128, 9,0, 147456);
  addw(dr1aw, W9[4],128,128, 9,0, 147456);
  addw(dr2aw, W9[5],128,128, 9,0, 147456);
  addw(er1bw, W1[0],128,128, 1,0, 16384);
  addw(er2bw, W1[1],128,128, 1,0, 16384);
  addw(dr1bw, W1[2],128,128, 1,0, 16384);
  addw(dr2bw, W1[3],128,128, 1,0, 16384);
  addw(dt1w,  Wdt1, 0,0,0,1, 262144);
  addw(cb,    cbBF, 0,0,0,2, 65536);
  addw(cb,    (u16*)cbn, 0,0,0,3, 512);
  addw(e1w,   (u16*)wsE1, 0,0,0,4, 6144);
  addw(dt2w,  Wb48, 0,0,0,5, 6144);
  wtab.n = ne;
  prep_w<<<(wtab.cum[ne] + 255)/256, 256, 0, stream>>>(wtab);

  // 3. e1
  conv_e1<<<2048, 256, 0, stream>>>(x, wsE1, e1b, BIGi);

  // taps
  Taps t16; t16.n = 16; t16.dh2 = 0; t16.dw2 = 0;
  for (int t=0;t<16;t++) { t16.dh2 |= (unsigned)(t>>2) << (2*t); t16.dw2 |= (unsigned)(t&3) << (2*t); }
  Taps t9; t9.n = 9; t9.dh2 = 0; t9.dw2 = 0;
  for (int t=0;t<9;t++) { t9.dh2 |= (unsigned)(t/3) << (2*t); t9.dw2 |= (unsigned)(t%3) << (2*t); }
  Taps t1x; t1x.n = 1; t1x.dh2 = 1; t1x.dw2 = 1;
  Taps tcm; tcm.n = 4; tcm.dh2 = 0; tcm.dw2 = 0;   // packed: 8 bits per class
  for (int cls=0; cls<4; ++cls) {
    int po = cls >> 1, pw = cls & 1;
    for (int tt=0; tt<4; ++tt) {
      int th = tt >> 1, tw = tt & 1;
      int dh = po ? (th ? 0 : 1) : (th ? -1 : 0);
      int dw = pw ? (tw ? 0 : 1) : (tw ? -1 : 0);
      tcm.dh2 |= (unsigned)(dh+1) << (8*cls + 2*tt);
      tcm.dw2 |= (unsigned)(dw+1) << (8*cls + 2*tt);
    }
  }

  auto conv = [&](const u16* in_, int iRS, int iIS, int si,
                  const u16* w_, const float* b_, Taps tp,
                  u16* o_, int oRS, int oIS, int so, int oh, int ow,
                  const u16* r_, u16* o2, int rl, float* zf, u16* zb) {
    conv_mfma<<<512, 256, 0, stream>>>(in_, iRS, iIS, si, w_, b_, tp,
                                       o_, oRS, oIS, so, oh, ow, r_, o2, rl, zf, zb, 0);
  };

  // encoder
  conv(BIGi, RS130, IS130, 2, W_e2, e2b, t16, Si[0], RS66, IS66, 1,0,0, nullptr, nullptr, 1, nullptr, nullptr); // e2 -> S0 (relu)
  conv(Si[0], RS66, IS66, 1, W9[0], e3b, t9, Si[1], RS66, IS66, 1,0,0, nullptr, Si[2], 0, nullptr, nullptr);    // e3 -> t2=S1, relu->S2
  conv(Si[2], RS66, IS66, 1, W9[1], er1ab, t9, Si[0], RS66, IS66, 1,0,0, nullptr, nullptr, 1, nullptr, nullptr);// er1a -> S0 (relu)
  conv(Si[0], RS66, IS66, 1, W1[0], er1bb, t1x, Si[3], RS66, IS66, 1,0,0, Si[1], Si[2], 0, nullptr, nullptr);   // er1b(+t2) -> t4=S3, relu->S2
  conv(Si[2], RS66, IS66, 1, W9[2], er2ab, t9, Si[0], RS66, IS66, 1,0,0, nullptr, nullptr, 1, nullptr, nullptr);// er2a -> S0 (relu)
  conv(Si[0], RS66, IS66, 1, W1[1], er2bb, t1x, nullptr, RS66, IS66, 1,0,0, Si[3], nullptr, 0, zeFc, zeBFc);    // er2b(+t4) -> ze compact (fp32+bf16)

  // VQ + outputs
  vq_score<<<dim3(512,4), 256, 0, stream>>>(zeBFc, cbBF, cbn, minb);
  finalize<<<1024, 256, 0, stream>>>(zeFc, minb, cb, out + 3145728, out + 11534336, Si[2]);  // zq bf16 -> S2

  // decoder
  conv(Si[2], RS66, IS66, 1, W9[3], d1b, t9, Si[0], RS66, IS66, 1,0,0, nullptr, Si[1], 0, nullptr, nullptr);    // d1 -> g1=S0, relu->S1
  conv(Si[1], RS66, IS66, 1, W9[4], dr1ab, t9, Si[2], RS66, IS66, 1,0,0, nullptr, nullptr, 1, nullptr, nullptr);// dr1a -> S2 (relu)
  conv(Si[2], RS66, IS66, 1, W1[2], dr1bb, t1x, Si[3], RS66, IS66, 1,0,0, Si[0], Si[1], 0, nullptr, nullptr);   // dr1b(+g1) -> g2=S3, relu->S1
  conv(Si[1], RS66, IS66, 1, W9[5], dr2ab, t9, Si[2], RS66, IS66, 1,0,0, nullptr, nullptr, 1, nullptr, nullptr);// dr2a -> S2 (relu)
  conv(Si[2], RS66, IS66, 1, W1[3], dr2bb, t1x, Si[0], RS66, IS66, 1,0,0, Si[3], nullptr, 0, nullptr, nullptr); // dr2b(+g2) -> g3=S0

  // dt1: 4 parity classes in one dispatch (blockIdx.y = cls)
  conv_mfma<<<dim3(512,4), 256, 0, stream>>>(Si[0], RS66, IS66, 1, Wdt1, dt1b, tcm,
                                             BIGi, RS130, IS130, 2, 0, 0,
                                             nullptr, nullptr, 1, nullptr, nullptr, 1);

  // dt2: cols GEMM (MFMA) + col2im gather
  dt2_gemm<<<1024, 256, 0, stream>>>(BIGi, Wb48, cols);
  dt2_gather<<<4096, 256, 0, stream>>>(cols, dt2b, out);
}